// Round 1
// baseline (9009.949 us; speedup 1.0000x reference)
//
#include <hip/hip_runtime.h>
#include <cstddef>

// Problem constants (from reference setup_inputs)
#define N_NODES 50000
#define N_EDGES 800000

// ---------------------------------------------------------------------------
// Degree count: cnt[dst]++ per edge (int atomics)
__global__ void count_k(const int* __restrict__ dst, int* __restrict__ cnt, int E) {
    int e = blockIdx.x * blockDim.x + threadIdx.x;
    if (e < E) atomicAdd(&cnt[dst[e]], 1);
}

// inv[i] = 1 / max(cnt[i], 1)
__global__ void inv_k(const int* __restrict__ cnt, float* __restrict__ inv, int N) {
    int i = blockIdx.x * blockDim.x + threadIdx.x;
    if (i < N) {
        int c = cnt[i];
        inv[i] = 1.0f / (float)(c > 0 ? c : 1);
    }
}

// Scatter mean: agg[dst] += x[src] * inv[dst], feature-parallel, float4 per thread.
// shift = log2(D/4). Coalesced gather of x row, coalesced atomics to agg row.
__global__ void scatter_mean_k(const float4* __restrict__ X4, const int* __restrict__ src,
                               const int* __restrict__ dst, const float* __restrict__ inv,
                               float* __restrict__ agg, int E, int shift) {
    int t = blockIdx.x * blockDim.x + threadIdx.x;
    int Dq = 1 << shift;
    int total = E << shift;
    if (t >= total) return;
    int e = t >> shift;
    int q = t & (Dq - 1);
    int s = src[e], d = dst[e];
    float4 v = X4[(size_t)s * Dq + q];
    float sc = inv[d];
    float* a = agg + (((size_t)d << shift) + (size_t)q) * 4;
    atomicAdd(a + 0, v.x * sc);
    atomicAdd(a + 1, v.y * sc);
    atomicAdd(a + 2, v.z * sc);
    atomicAdd(a + 3, v.w * sc);
}

// ---------------------------------------------------------------------------
// Fused SAGE layer GEMM: out[i,o] = tanh(mean[i,:]·Wl[o,:] + x[i,:]·Wr[o,:] + b[o])
// Treated as one K=2*Kd GEMM. fp32 vector ALU, 64x64 block tile, BK=32,
// 256 threads, 4x4 micro-tile, float4 LDS reads ([m][k] layout, padded).
#define BM 64
#define BN 64
#define BK 32

__global__ __launch_bounds__(256)
void sage_layer_k(const float* __restrict__ mean, const float* __restrict__ xin,
                  const float* __restrict__ Wl, const float* __restrict__ Wr,
                  const float* __restrict__ bias, float* __restrict__ out,
                  int N, int Kd, int Md) {
    __shared__ float As[BM][BK + 4];   // +4 pad: keeps float4 alignment, spreads banks
    __shared__ float Bs[BN][BK + 4];

    const int tid = threadIdx.x;
    const int ty = tid >> 4;           // 0..15 (row group)
    const int tx = tid & 15;           // 0..15 (col group)
    const int rowBase = blockIdx.x * BM;
    const int colBase = blockIdx.y * BN;

    float acc[4][4] = {};

    for (int k0 = 0; k0 < 2 * Kd; k0 += BK) {
        const float* Aptr; const float* Bptr; int ko;
        if (k0 < Kd) { Aptr = mean; Bptr = Wl; ko = k0; }
        else         { Aptr = xin;  Bptr = Wr; ko = k0 - Kd; }

        // Stage 64x32 A tile and 64x32 B tile; 2 float4 each per thread.
        #pragma unroll
        for (int l = 0; l < 2; l++) {
            int f  = tid + l * 256;    // 0..511
            int r  = f >> 3;           // 0..63
            int kq = f & 7;            // float4 index within k-chunk
            int gr = rowBase + r;
            float4 v = make_float4(0.f, 0.f, 0.f, 0.f);
            if (gr < N) v = *(const float4*)(Aptr + (size_t)gr * Kd + ko + kq * 4);
            *(float4*)&As[r][kq * 4] = v;
            int gc = colBase + r;      // always < Md (grid exact in y)
            float4 wv = *(const float4*)(Bptr + (size_t)gc * Kd + ko + kq * 4);
            *(float4*)&Bs[r][kq * 4] = wv;
        }
        __syncthreads();

        #pragma unroll
        for (int kc = 0; kc < BK; kc += 4) {
            float4 a4[4], b4[4];
            #pragma unroll
            for (int i = 0; i < 4; i++) a4[i] = *(const float4*)&As[ty * 4 + i][kc];
            #pragma unroll
            for (int j = 0; j < 4; j++) b4[j] = *(const float4*)&Bs[tx * 4 + j][kc];
            #pragma unroll
            for (int i = 0; i < 4; i++)
                #pragma unroll
                for (int j = 0; j < 4; j++)
                    acc[i][j] += a4[i].x * b4[j].x + a4[i].y * b4[j].y
                               + a4[i].z * b4[j].z + a4[i].w * b4[j].w;
        }
        __syncthreads();
    }

    // Epilogue: bias + tanh, float4 stores
    #pragma unroll
    for (int i = 0; i < 4; i++) {
        int gr = rowBase + ty * 4 + i;
        if (gr >= N) continue;
        int gc0 = colBase + tx * 4;
        float4 o;
        o.x = tanhf(acc[i][0] + bias[gc0 + 0]);
        o.y = tanhf(acc[i][1] + bias[gc0 + 1]);
        o.z = tanhf(acc[i][2] + bias[gc0 + 2]);
        o.w = tanhf(acc[i][3] + bias[gc0 + 3]);
        *(float4*)(out + (size_t)gr * Md + gc0) = o;
    }
}

// ---------------------------------------------------------------------------
extern "C" void kernel_launch(void* const* d_in, const int* in_sizes, int n_in,
                              void* d_out, int out_size, void* d_ws, size_t ws_size,
                              hipStream_t stream) {
    const int N = N_NODES, E = N_EDGES;

    const float* x[2]   = {(const float*)d_in[0],  (const float*)d_in[1]};
    const int*   ei[2]  = {(const int*)d_in[2],    (const int*)d_in[3]};
    const float* W1l[2] = {(const float*)d_in[4],  (const float*)d_in[10]};
    const float* b1[2]  = {(const float*)d_in[5],  (const float*)d_in[11]};
    const float* W1r[2] = {(const float*)d_in[6],  (const float*)d_in[12]};
    const float* W2l[2] = {(const float*)d_in[7],  (const float*)d_in[13]};
    const float* b2[2]  = {(const float*)d_in[8],  (const float*)d_in[14]};
    const float* W2r[2] = {(const float*)d_in[9],  (const float*)d_in[15]};
    float* out = (float*)d_out;

    // Workspace layout:
    //   [0, 256KB)          cnt   (N ints)
    //   [256KB, 512KB)      inv   (N floats)
    //   [512KB, +51.2MB)    agg   (N x 256 f32, reused for both layers)
    //   [.., +51.2MB)       h     (N x 256 f32 hidden activations)
    char* wsb = (char*)d_ws;
    int*   cnt = (int*)wsb;
    float* inv = (float*)(wsb + (256 << 10));
    float* agg = (float*)(wsb + (512 << 10));
    float* h   = (float*)(wsb + (512 << 10) + (size_t)N * 256 * sizeof(float));

    const int gemm_rows = (N + BM - 1) / BM;   // 782

    for (int g = 0; g < 2; g++) {
        const int* src = ei[g];
        const int* dst = ei[g] + E;

        // Degree counts + reciprocal (shared by both layers of this graph)
        hipMemsetAsync(cnt, 0, (size_t)N * sizeof(int), stream);
        count_k<<<(E + 255) / 256, 256, 0, stream>>>(dst, cnt, E);
        inv_k<<<(N + 255) / 256, 256, 0, stream>>>(cnt, inv, N);

        // ---- Layer 1: aggregate x (D=128), GEMM K=128 -> 256, tanh -> h
        hipMemsetAsync(agg, 0, (size_t)N * 128 * sizeof(float), stream);
        {
            int total = E << 5;  // E * 32 float4-threads
            scatter_mean_k<<<(total + 255) / 256, 256, 0, stream>>>(
                (const float4*)x[g], src, dst, inv, agg, E, 5);
        }
        sage_layer_k<<<dim3(gemm_rows, 256 / BN), 256, 0, stream>>>(
            agg, x[g], W1l[g], W1r[g], b1[g], h, N, 128, 256);

        // ---- Layer 2: aggregate h (D=256), GEMM K=256 -> 128, tanh -> out
        hipMemsetAsync(agg, 0, (size_t)N * 256 * sizeof(float), stream);
        {
            int total = E << 6;  // E * 64 float4-threads
            scatter_mean_k<<<(total + 255) / 256, 256, 0, stream>>>(
                (const float4*)h, src, dst, inv, agg, E, 6);
        }
        sage_layer_k<<<dim3(gemm_rows, 128 / BN), 256, 0, stream>>>(
            agg, h, W2l[g], W2r[g], b2[g], out + (size_t)g * N * 128, N, 256, 128);
    }
}

// Round 2
// 1499.049 us; speedup vs baseline: 6.0104x; 6.0104x over previous
//
#include <hip/hip_runtime.h>
#include <cstddef>

// Problem constants (from reference setup_inputs)
#define N_NODES 50000
#define N_EDGES 800000

// ---------------------------------------------------------------------------
// fast tanh via v_exp_f32: (e^{2x}-1)/(e^{2x}+1) = 1 - 2/(e^{2x}+1)
// Saturates correctly at +-inf; abs err ~1e-7, threshold is 2e-2.
__device__ __forceinline__ float fast_tanh(float x) {
    float t = __expf(2.0f * x);
    return 1.0f - 2.0f / (t + 1.0f);
}

// ---------------------------------------------------------------------------
// Degree count: cnt[dst]++ per edge (int atomics)
__global__ void count_k(const int* __restrict__ dst, int* __restrict__ cnt, int E) {
    int e = blockIdx.x * blockDim.x + threadIdx.x;
    if (e < E) atomicAdd(&cnt[dst[e]], 1);
}

// Single-block exclusive scan over cnt -> rowptr[N+1], and pos[i]=rowptr[i]
__global__ __launch_bounds__(1024) void scan_k(const int* __restrict__ cnt,
                                               int* __restrict__ rowptr,
                                               int* __restrict__ pos, int N) {
    __shared__ int partial[1024];
    int tid = threadIdx.x;
    int chunk = (N + 1023) >> 10;
    int begin = tid * chunk;
    int end = begin + chunk; if (end > N) end = N;
    int s = 0;
    if (begin < N) for (int i = begin; i < end; i++) s += cnt[i];
    partial[tid] = s;
    __syncthreads();
    // Hillis-Steele inclusive scan over 1024 partials
    for (int off = 1; off < 1024; off <<= 1) {
        int v = (tid >= off) ? partial[tid - off] : 0;
        __syncthreads();
        partial[tid] += v;
        __syncthreads();
    }
    int base = (tid == 0) ? 0 : partial[tid - 1];
    if (begin < N) {
        for (int i = begin; i < end; i++) {
            rowptr[i] = base; pos[i] = base;
            base += cnt[i];
        }
    }
    if (tid == 0) rowptr[N] = partial[1023];
}

// Counting-sort scatter: adj[slot] = src, bucketed by dst (int atomics only)
__global__ void fill_adj_k(const int* __restrict__ src, const int* __restrict__ dst,
                           int* __restrict__ pos, int* __restrict__ adj, int E) {
    int e = blockIdx.x * blockDim.x + threadIdx.x;
    if (e < E) {
        int slot = atomicAdd(&pos[dst[e]], 1);
        adj[slot] = src[e];
    }
}

// Pull-mean aggregation, D=128: one wave per node, lane owns float2.
// Coalesced 512B row gathers from L2/L3-resident table, register accumulate.
__global__ __launch_bounds__(256) void gather_mean128_k(
        const float* __restrict__ X, const int* __restrict__ rowptr,
        const int* __restrict__ adj, float* __restrict__ out, int N) {
    int gw = (blockIdx.x * blockDim.x + threadIdx.x) >> 6;   // global wave = node
    int lane = threadIdx.x & 63;
    if (gw >= N) return;
    int beg = rowptr[gw], end = rowptr[gw + 1];
    const float2* X2 = (const float2*)X;
    float sx = 0.f, sy = 0.f;
    int n = beg;
    for (; n + 4 <= end; n += 4) {             // 4 rows in flight for MLP
        int s0 = adj[n], s1 = adj[n + 1], s2 = adj[n + 2], s3 = adj[n + 3];
        float2 v0 = X2[(size_t)s0 * 64 + lane];
        float2 v1 = X2[(size_t)s1 * 64 + lane];
        float2 v2 = X2[(size_t)s2 * 64 + lane];
        float2 v3 = X2[(size_t)s3 * 64 + lane];
        sx += v0.x + v1.x + v2.x + v3.x;
        sy += v0.y + v1.y + v2.y + v3.y;
    }
    for (; n < end; n++) {
        float2 v = X2[(size_t)adj[n] * 64 + lane];
        sx += v.x; sy += v.y;
    }
    int deg = end - beg;
    float inv = 1.0f / (float)(deg > 0 ? deg : 1);
    float2 o; o.x = sx * inv; o.y = sy * inv;
    ((float2*)out)[(size_t)gw * 64 + lane] = o;
}

// ---------------------------------------------------------------------------
// Generic fused GEMM: out[r,c] = act( A1[r,:]·B1[c,:] + A2[r,:]·B2[c,:]
//                                     + add[r,c] + bias[c] )
// A1:[N][K1], B1:[Md][K1], A2:[N][K2], B2:[Md][K2] (K2 may be 0).
// fp32 vector ALU, 64x64 tile, BK=32, 256 threads, 4x4 micro-tile.
#define BM 64
#define BN 64
#define BK 32

template <bool TANH, bool HAS_ADD>
__global__ __launch_bounds__(256)
void gemm_k(const float* __restrict__ A1, const float* __restrict__ B1, int K1,
            const float* __restrict__ A2, const float* __restrict__ B2, int K2,
            const float* __restrict__ add, const float* __restrict__ bias,
            float* __restrict__ out, int N, int Md) {
    __shared__ float As[BM][BK + 4];
    __shared__ float Bs[BN][BK + 4];

    const int tid = threadIdx.x;
    const int ty = tid >> 4;           // 0..15
    const int tx = tid & 15;           // 0..15
    const int rowBase = blockIdx.x * BM;
    const int colBase = blockIdx.y * BN;

    float acc[4][4] = {};

    for (int k0 = 0; k0 < K1 + K2; k0 += BK) {
        const float* Aptr; const float* Bptr; int ko, ld;
        if (k0 < K1) { Aptr = A1; Bptr = B1; ko = k0;      ld = K1; }
        else         { Aptr = A2; Bptr = B2; ko = k0 - K1; ld = K2; }

        #pragma unroll
        for (int l = 0; l < 2; l++) {
            int f  = tid + l * 256;    // 0..511
            int r  = f >> 3;           // 0..63
            int kq = f & 7;
            int gr = rowBase + r;
            float4 v = make_float4(0.f, 0.f, 0.f, 0.f);
            if (gr < N) v = *(const float4*)(Aptr + (size_t)gr * ld + ko + kq * 4);
            *(float4*)&As[r][kq * 4] = v;
            int gc = colBase + r;      // grid exact in y
            float4 wv = *(const float4*)(Bptr + (size_t)gc * ld + ko + kq * 4);
            *(float4*)&Bs[r][kq * 4] = wv;
        }
        __syncthreads();

        #pragma unroll
        for (int kc = 0; kc < BK; kc += 4) {
            float4 a4[4], b4[4];
            #pragma unroll
            for (int i = 0; i < 4; i++) a4[i] = *(const float4*)&As[ty * 4 + i][kc];
            #pragma unroll
            for (int j = 0; j < 4; j++) b4[j] = *(const float4*)&Bs[tx * 4 + j][kc];
            #pragma unroll
            for (int i = 0; i < 4; i++)
                #pragma unroll
                for (int j = 0; j < 4; j++)
                    acc[i][j] += a4[i].x * b4[j].x + a4[i].y * b4[j].y
                               + a4[i].z * b4[j].z + a4[i].w * b4[j].w;
        }
        __syncthreads();
    }

    #pragma unroll
    for (int i = 0; i < 4; i++) {
        int gr = rowBase + ty * 4 + i;
        if (gr >= N) continue;
        int gc0 = colBase + tx * 4;
        float4 r = make_float4(acc[i][0], acc[i][1], acc[i][2], acc[i][3]);
        if (HAS_ADD) {
            float4 ad = *(const float4*)(add + (size_t)gr * Md + gc0);
            r.x += ad.x; r.y += ad.y; r.z += ad.z; r.w += ad.w;
        }
        if (bias) {
            r.x += bias[gc0 + 0]; r.y += bias[gc0 + 1];
            r.z += bias[gc0 + 2]; r.w += bias[gc0 + 3];
        }
        if (TANH) {
            r.x = fast_tanh(r.x); r.y = fast_tanh(r.y);
            r.z = fast_tanh(r.z); r.w = fast_tanh(r.w);
        }
        *(float4*)(out + (size_t)gr * Md + gc0) = r;
    }
}

// ---------------------------------------------------------------------------
extern "C" void kernel_launch(void* const* d_in, const int* in_sizes, int n_in,
                              void* d_out, int out_size, void* d_ws, size_t ws_size,
                              hipStream_t stream) {
    const int N = N_NODES, E = N_EDGES;

    const float* x[2]   = {(const float*)d_in[0],  (const float*)d_in[1]};
    const int*   ei[2]  = {(const int*)d_in[2],    (const int*)d_in[3]};
    const float* W1l[2] = {(const float*)d_in[4],  (const float*)d_in[10]};
    const float* b1[2]  = {(const float*)d_in[5],  (const float*)d_in[11]};
    const float* W1r[2] = {(const float*)d_in[6],  (const float*)d_in[12]};
    const float* W2l[2] = {(const float*)d_in[7],  (const float*)d_in[13]};
    const float* b2[2]  = {(const float*)d_in[8],  (const float*)d_in[14]};
    const float* W2r[2] = {(const float*)d_in[9],  (const float*)d_in[15]};
    float* out = (float*)d_out;

    // Workspace layout (reused across both graphs):
    //   cnt    [0,      256K)   N ints
    //   rowptr [256K,   512K)   N+1 ints
    //   pos    [512K,   768K)   N ints
    //   adj    [768K,   4M)     E ints (3.2MB)
    //   bufA   [4M,     +25.6M) N x 128 f32 : mean1, later z
    //   bufB   [+25.6M, +25.6M) N x 128 f32 : aggz
    //   h      [..,     +51.2M) N x 256 f32
    char* wsb = (char*)d_ws;
    int*   cnt    = (int*)(wsb);
    int*   rowptr = (int*)(wsb + (256 << 10));
    int*   pos    = (int*)(wsb + (512 << 10));
    int*   adj    = (int*)(wsb + (768 << 10));
    float* bufA   = (float*)(wsb + (4 << 20));
    float* bufB   = (float*)(wsb + (4 << 20) + (size_t)N * 128 * sizeof(float));
    float* h      = (float*)(wsb + (4 << 20) + 2 * (size_t)N * 128 * sizeof(float));

    const int gemm_rows = (N + BM - 1) / BM;   // 782
    const int agg_blocks = (N * 64 + 255) / 256;  // wave-per-node, 4 nodes/block

    for (int g = 0; g < 2; g++) {
        const int* src = ei[g];
        const int* dst = ei[g] + E;

        // ---- CSR build (counting sort by dst)
        hipMemsetAsync(cnt, 0, (size_t)N * sizeof(int), stream);
        count_k<<<(E + 255) / 256, 256, 0, stream>>>(dst, cnt, E);
        scan_k<<<1, 1024, 0, stream>>>(cnt, rowptr, pos, N);
        fill_adj_k<<<(E + 255) / 256, 256, 0, stream>>>(src, dst, pos, adj, E);

        // ---- Layer 1: mean1 = mean-agg(x) [D=128]
        gather_mean128_k<<<agg_blocks, 256, 0, stream>>>(x[g], rowptr, adj, bufA, N);
        // h = tanh(mean1@W1l^T + x@W1r^T + b1)   [K=128+128 -> 256]
        gemm_k<true, false><<<dim3(gemm_rows, 256 / BN), 256, 0, stream>>>(
            bufA, W1l[g], 128, x[g], W1r[g], 128, nullptr, b1[g], h, N, 256);

        // ---- Layer 2 (linearity trick): z = h@W2l^T first, then aggregate z
        gemm_k<false, false><<<dim3(gemm_rows, 128 / BN), 256, 0, stream>>>(
            h, W2l[g], 256, nullptr, nullptr, 0, nullptr, nullptr, bufA, N, 128);
        // aggz = mean-agg(z) [D=128]
        gather_mean128_k<<<agg_blocks, 256, 0, stream>>>(bufA, rowptr, adj, bufB, N);
        // out = tanh(aggz + h@W2r^T + b2)   [K=256 -> 128]
        gemm_k<true, true><<<dim3(gemm_rows, 128 / BN), 256, 0, stream>>>(
            h, W2r[g], 256, nullptr, nullptr, 0, bufB, b2[g],
            out + (size_t)g * N * 128, N, 128);
    }
}

// Round 4
// 1029.142 us; speedup vs baseline: 8.7548x; 1.4566x over previous
//
#include <hip/hip_runtime.h>
#include <cstddef>

// Problem constants (from reference setup_inputs)
#define N_NODES 50000
#define N_EDGES 800000

typedef __attribute__((ext_vector_type(8))) short short8;   // 8 bf16 (4 VGPRs)
typedef __attribute__((ext_vector_type(4))) short short4v;  // 4 bf16
typedef __attribute__((ext_vector_type(4))) float f32x4;    // MFMA acc

// ---------------------------------------------------------------------------
// fast tanh via v_exp_f32; abs err ~1e-7, threshold is 2e-2.
__device__ __forceinline__ float fast_tanh(float x) {
    float t = __expf(2.0f * x);
    return 1.0f - 2.0f / (t + 1.0f);
}

// round-to-nearest-even f32 -> bf16 bit pattern
__device__ __forceinline__ short bf16_rne(float x) {
    unsigned u = __float_as_uint(x);
    unsigned r = u + 0x7FFFu + ((u >> 16) & 1u);
    return (short)(r >> 16);
}
// split x ~= hi + lo (both bf16); hi rounded RNE, lo = bf16(x - hi).
// Returns {hi, lo} by value (vector elements can't bind to references).
__device__ __forceinline__ short2 split2(float x) {
    unsigned u = __float_as_uint(x);
    unsigned r = (u + 0x7FFFu + ((u >> 16) & 1u)) & 0xFFFF0000u;
    short2 p;
    p.x = (short)(r >> 16);
    p.y = bf16_rne(x - __uint_as_float(r));
    return p;
}

// ---------------------------------------------------------------------------
// Degree count: cnt[dst]++ per edge (int atomics)
__global__ void count_k(const int* __restrict__ dst, int* __restrict__ cnt, int E) {
    int e = blockIdx.x * blockDim.x + threadIdx.x;
    if (e < E) atomicAdd(&cnt[dst[e]], 1);
}

// Single-block exclusive scan over cnt -> rowptr[N+1], and pos[i]=rowptr[i]
__global__ __launch_bounds__(1024) void scan_k(const int* __restrict__ cnt,
                                               int* __restrict__ rowptr,
                                               int* __restrict__ pos, int N) {
    __shared__ int partial[1024];
    int tid = threadIdx.x;
    int chunk = (N + 1023) >> 10;
    int begin = tid * chunk;
    int end = begin + chunk; if (end > N) end = N;
    int s = 0;
    if (begin < N) for (int i = begin; i < end; i++) s += cnt[i];
    partial[tid] = s;
    __syncthreads();
    for (int off = 1; off < 1024; off <<= 1) {
        int v = (tid >= off) ? partial[tid - off] : 0;
        __syncthreads();
        partial[tid] += v;
        __syncthreads();
    }
    int base = (tid == 0) ? 0 : partial[tid - 1];
    if (begin < N) {
        for (int i = begin; i < end; i++) {
            rowptr[i] = base; pos[i] = base;
            base += cnt[i];
        }
    }
    if (tid == 0) rowptr[N] = partial[1023];
}

// Counting-sort scatter: adj[slot] = src, bucketed by dst (int atomics only)
__global__ void fill_adj_k(const int* __restrict__ src, const int* __restrict__ dst,
                           int* __restrict__ pos, int* __restrict__ adj, int E) {
    int e = blockIdx.x * blockDim.x + threadIdx.x;
    if (e < E) {
        int slot = atomicAdd(&pos[dst[e]], 1);
        adj[slot] = src[e];
    }
}

// Pull-mean aggregation, D=128: one wave per node, lane owns float2.
__global__ __launch_bounds__(256) void gather_mean128_k(
        const float* __restrict__ X, const int* __restrict__ rowptr,
        const int* __restrict__ adj, float* __restrict__ out, int N) {
    int gw = (blockIdx.x * blockDim.x + threadIdx.x) >> 6;   // global wave = node
    int lane = threadIdx.x & 63;
    if (gw >= N) return;
    int beg = rowptr[gw], end = rowptr[gw + 1];
    const float2* X2 = (const float2*)X;
    float sx = 0.f, sy = 0.f;
    int n = beg;
    for (; n + 4 <= end; n += 4) {
        int s0 = adj[n], s1 = adj[n + 1], s2 = adj[n + 2], s3 = adj[n + 3];
        float2 v0 = X2[(size_t)s0 * 64 + lane];
        float2 v1 = X2[(size_t)s1 * 64 + lane];
        float2 v2 = X2[(size_t)s2 * 64 + lane];
        float2 v3 = X2[(size_t)s3 * 64 + lane];
        sx += v0.x + v1.x + v2.x + v3.x;
        sy += v0.y + v1.y + v2.y + v3.y;
    }
    for (; n < end; n++) {
        float2 v = X2[(size_t)adj[n] * 64 + lane];
        sx += v.x; sy += v.y;
    }
    int deg = end - beg;
    float inv = 1.0f / (float)(deg > 0 ? deg : 1);
    float2 o; o.x = sx * inv; o.y = sy * inv;
    ((float2*)out)[(size_t)gw * 64 + lane] = o;
}

// ---------------------------------------------------------------------------
// Split-bf16 MFMA fused GEMM:
//   out[r,c] = act( A1[r,:]·B1[c,:] + A2[r,:]·B2[c,:] + add[r,c] + bias[c] )
// fp32 inputs converted to bf16 hi+lo during LDS staging; 3 MFMAs per site
// (Ah·Bh + Ah·Bl + Al·Bh) ~= fp32 accuracy. 128x128 tile, BK=32, 4 waves,
// each wave 64x64 via 4x4 grid of 16x16x32 mfma.
#define TM 128
#define TN 128
#define TK 32
#define LSTR 40   // LDS row stride in shorts (32 data + 8 pad; 80B, 16B-aligned)

template <bool TANH, bool HAS_ADD>
__global__ __launch_bounds__(256)
void gemm_mfma_k(const float* __restrict__ A1, const float* __restrict__ B1, int K1,
                 const float* __restrict__ A2, const float* __restrict__ B2, int K2,
                 const float* __restrict__ add, const float* __restrict__ bias,
                 float* __restrict__ out, int N, int Md) {
    __shared__ short Ah[TM][LSTR], Al[TM][LSTR];
    __shared__ short Bh[TN][LSTR], Bl[TN][LSTR];

    const int tid = threadIdx.x;
    const int lane = tid & 63;
    const int wave = tid >> 6;              // 0..3
    const int waveM = (wave & 1) * 64;
    const int waveN = (wave >> 1) * 64;
    const int rowBase = blockIdx.x * TM;
    const int colBase = blockIdx.y * TN;

    f32x4 acc[4][4] = {{0.f, 0.f, 0.f, 0.f}};

    const int srow = tid >> 3;              // 0..31 (staging row group)
    const int scol = (tid & 7) * 4;         // float4 column within 32-wide k-chunk

    for (int k0 = 0; k0 < K1 + K2; k0 += TK) {
        const float* Ap; const float* Bp; int ko, ld;
        if (k0 < K1) { Ap = A1; Bp = B1; ko = k0;      ld = K1; }
        else         { Ap = A2; Bp = B2; ko = k0 - K1; ld = K2; }

        // Stage 128x32 A and B tiles as bf16 hi/lo (4 rows per thread, 32 apart)
        #pragma unroll
        for (int i = 0; i < 4; i++) {
            int r = srow + 32 * i;
            // A (bounds-checked rows)
            float4 av = make_float4(0.f, 0.f, 0.f, 0.f);
            int gr = rowBase + r;
            if (gr < N) av = *(const float4*)(Ap + (size_t)gr * ld + ko + scol);
            short4v ah, al;
            short2 p;
            p = split2(av.x); ah.x = p.x; al.x = p.y;
            p = split2(av.y); ah.y = p.x; al.y = p.y;
            p = split2(av.z); ah.z = p.x; al.z = p.y;
            p = split2(av.w); ah.w = p.x; al.w = p.y;
            *(short4v*)&Ah[r][scol] = ah;
            *(short4v*)&Al[r][scol] = al;
            // B (grid exact in cols)
            float4 bv = *(const float4*)(Bp + (size_t)(colBase + r) * ld + ko + scol);
            short4v bh, bl;
            p = split2(bv.x); bh.x = p.x; bl.x = p.y;
            p = split2(bv.y); bh.y = p.x; bl.y = p.y;
            p = split2(bv.z); bh.z = p.x; bl.z = p.y;
            p = split2(bv.w); bh.w = p.x; bl.w = p.y;
            *(short4v*)&Bh[r][scol] = bh;
            *(short4v*)&Bl[r][scol] = bl;
        }
        __syncthreads();

        // Fragments: A[m = lane&15][k = (lane>>4)*8 + j]
        const int fm = lane & 15;
        const int fq = (lane >> 4) * 8;
        short8 fah[4], fal[4], fbh[4], fbl[4];
        #pragma unroll
        for (int mi = 0; mi < 4; mi++) {
            fah[mi] = *(const short8*)&Ah[waveM + mi * 16 + fm][fq];
            fal[mi] = *(const short8*)&Al[waveM + mi * 16 + fm][fq];
        }
        #pragma unroll
        for (int ni = 0; ni < 4; ni++) {
            fbh[ni] = *(const short8*)&Bh[waveN + ni * 16 + fm][fq];
            fbl[ni] = *(const short8*)&Bl[waveN + ni * 16 + fm][fq];
        }

        #pragma unroll
        for (int mi = 0; mi < 4; mi++)
            #pragma unroll
            for (int ni = 0; ni < 4; ni++) {
                acc[mi][ni] = __builtin_amdgcn_mfma_f32_16x16x32_bf16(
                    fah[mi], fbh[ni], acc[mi][ni], 0, 0, 0);
                acc[mi][ni] = __builtin_amdgcn_mfma_f32_16x16x32_bf16(
                    fah[mi], fbl[ni], acc[mi][ni], 0, 0, 0);
                acc[mi][ni] = __builtin_amdgcn_mfma_f32_16x16x32_bf16(
                    fal[mi], fbh[ni], acc[mi][ni], 0, 0, 0);
            }
        __syncthreads();
    }

    // Epilogue. C/D layout (16x16): col = lane&15, row = (lane>>4)*4 + reg.
    const int orow0 = rowBase + waveM + (lane >> 4) * 4;
    const int ocol0 = colBase + waveN + (lane & 15);
    #pragma unroll
    for (int ni = 0; ni < 4; ni++) {
        int col = ocol0 + ni * 16;
        float bv = bias ? bias[col] : 0.0f;
        #pragma unroll
        for (int mi = 0; mi < 4; mi++) {
            #pragma unroll
            for (int r = 0; r < 4; r++) {
                int row = orow0 + mi * 16 + r;
                if (row >= N) continue;
                float v = acc[mi][ni][r] + bv;
                if (HAS_ADD) v += add[(size_t)row * Md + col];
                if (TANH) v = fast_tanh(v);
                out[(size_t)row * Md + col] = v;
            }
        }
    }
}

// ---------------------------------------------------------------------------
extern "C" void kernel_launch(void* const* d_in, const int* in_sizes, int n_in,
                              void* d_out, int out_size, void* d_ws, size_t ws_size,
                              hipStream_t stream) {
    const int N = N_NODES, E = N_EDGES;

    const float* x[2]   = {(const float*)d_in[0],  (const float*)d_in[1]};
    const int*   ei[2]  = {(const int*)d_in[2],    (const int*)d_in[3]};
    const float* W1l[2] = {(const float*)d_in[4],  (const float*)d_in[10]};
    const float* b1[2]  = {(const float*)d_in[5],  (const float*)d_in[11]};
    const float* W1r[2] = {(const float*)d_in[6],  (const float*)d_in[12]};
    const float* W2l[2] = {(const float*)d_in[7],  (const float*)d_in[13]};
    const float* b2[2]  = {(const float*)d_in[8],  (const float*)d_in[14]};
    const float* W2r[2] = {(const float*)d_in[9],  (const float*)d_in[15]};
    float* out = (float*)d_out;

    // Workspace layout (reused across both graphs):
    //   cnt    [0,      256K)   N ints
    //   rowptr [256K,   512K)   N+1 ints
    //   pos    [512K,   768K)   N ints
    //   adj    [768K,   4M)     E ints (3.2MB)
    //   bufA   [4M,     +25.6M) N x 128 f32 : mean1, later z
    //   bufB   [+,      +25.6M) N x 128 f32 : aggz
    //   h      [+,      +51.2M) N x 256 f32
    char* wsb = (char*)d_ws;
    int*   cnt    = (int*)(wsb);
    int*   rowptr = (int*)(wsb + (256 << 10));
    int*   pos    = (int*)(wsb + (512 << 10));
    int*   adj    = (int*)(wsb + (768 << 10));
    float* bufA   = (float*)(wsb + (4 << 20));
    float* bufB   = (float*)(wsb + (4 << 20) + (size_t)N * 128 * sizeof(float));
    float* h      = (float*)(wsb + (4 << 20) + 2 * (size_t)N * 128 * sizeof(float));

    const int gemm_rows = (N + TM - 1) / TM;      // 391
    const int agg_blocks = (N * 64 + 255) / 256;  // wave-per-node

    for (int g = 0; g < 2; g++) {
        const int* src = ei[g];
        const int* dst = ei[g] + E;

        // ---- CSR build (counting sort by dst)
        (void)hipMemsetAsync(cnt, 0, (size_t)N * sizeof(int), stream);
        count_k<<<(E + 255) / 256, 256, 0, stream>>>(dst, cnt, E);
        scan_k<<<1, 1024, 0, stream>>>(cnt, rowptr, pos, N);
        fill_adj_k<<<(E + 255) / 256, 256, 0, stream>>>(src, dst, pos, adj, E);

        // ---- Layer 1: mean1 = mean-agg(x) [D=128]
        gather_mean128_k<<<agg_blocks, 256, 0, stream>>>(x[g], rowptr, adj, bufA, N);
        // h = tanh(mean1@W1l^T + x@W1r^T + b1)   [K=128+128 -> 256]
        gemm_mfma_k<true, false><<<dim3(gemm_rows, 256 / TN), 256, 0, stream>>>(
            bufA, W1l[g], 128, x[g], W1r[g], 128, nullptr, b1[g], h, N, 256);

        // ---- Layer 2 (linearity): z = h@W2l^T first, then aggregate z
        gemm_mfma_k<false, false><<<dim3(gemm_rows, 128 / TN), 256, 0, stream>>>(
            h, W2l[g], 256, nullptr, nullptr, 0, nullptr, nullptr, bufA, N, 128);
        // aggz = mean-agg(z) [D=128]
        gather_mean128_k<<<agg_blocks, 256, 0, stream>>>(bufA, rowptr, adj, bufB, N);
        // out = tanh(aggz + h@W2r^T + b2)   [K=256 -> 128]
        gemm_mfma_k<true, true><<<dim3(gemm_rows, 128 / TN), 256, 0, stream>>>(
            h, W2r[g], 256, nullptr, nullptr, 0, bufB, b2[g],
            out + (size_t)g * N * 128, N, 128);
    }
}

// Round 5
// 833.882 us; speedup vs baseline: 10.8048x; 1.2342x over previous
//
#include <hip/hip_runtime.h>
#include <cstddef>

// Problem constants (from reference setup_inputs)
#define N_NODES 50000
#define N_EDGES 800000

typedef __attribute__((ext_vector_type(8))) short short8;   // 8 bf16 (4 VGPRs)
typedef __attribute__((ext_vector_type(4))) short short4v;  // 4 bf16
typedef __attribute__((ext_vector_type(4))) float f32x4;    // MFMA acc

// ---------------------------------------------------------------------------
// fast tanh via v_exp_f32; abs err ~1e-7, threshold is 2e-2.
__device__ __forceinline__ float fast_tanh(float x) {
    float t = __expf(2.0f * x);
    return 1.0f - 2.0f / (t + 1.0f);
}

// round-to-nearest-even f32 -> bf16 bit pattern
__device__ __forceinline__ short bf16_rne(float x) {
    unsigned u = __float_as_uint(x);
    unsigned r = u + 0x7FFFu + ((u >> 16) & 1u);
    return (short)(r >> 16);
}
// split x ~= hi + lo (both bf16); hi rounded RNE, lo = bf16(x - hi).
__device__ __forceinline__ short2 split2(float x) {
    unsigned u = __float_as_uint(x);
    unsigned r = (u + 0x7FFFu + ((u >> 16) & 1u)) & 0xFFFF0000u;
    short2 p;
    p.x = (short)(r >> 16);
    p.y = bf16_rne(x - __uint_as_float(r));
    return p;
}

// ---------------------------------------------------------------------------
// Degree count: cnt[dst]++ per edge (int atomics)
__global__ void count_k(const int* __restrict__ dst, int* __restrict__ cnt, int E) {
    int e = blockIdx.x * blockDim.x + threadIdx.x;
    if (e < E) atomicAdd(&cnt[dst[e]], 1);
}

// ---- 3-phase grid scan (replaces the 110us single-block scan) -------------
#define SCAN_NB ((N_NODES + 255) / 256)   // 196 blocks

// Phase 1: per-block sum of cnt -> bsum[b]
__global__ __launch_bounds__(256) void bsum_k(const int* __restrict__ cnt,
                                              int* __restrict__ bsum, int N) {
    __shared__ int red[256];
    int i = blockIdx.x * 256 + threadIdx.x;
    int v = (i < N) ? cnt[i] : 0;
    red[threadIdx.x] = v;
    __syncthreads();
    #pragma unroll
    for (int off = 128; off > 0; off >>= 1) {
        if (threadIdx.x < off) red[threadIdx.x] += red[threadIdx.x + off];
        __syncthreads();
    }
    if (threadIdx.x == 0) bsum[blockIdx.x] = red[0];
}

// Phase 2: single small block scans nb (<=256) block sums -> exclusive boff;
// also writes rowptr[N] = total.
__global__ __launch_bounds__(256) void boff_k(const int* __restrict__ bsum,
                                              int* __restrict__ boff,
                                              int* __restrict__ rowptr,
                                              int nb, int N) {
    __shared__ int s[256];
    int tid = threadIdx.x;
    int v = (tid < nb) ? bsum[tid] : 0;
    s[tid] = v;
    __syncthreads();
    #pragma unroll
    for (int off = 1; off < 256; off <<= 1) {
        int t = (tid >= off) ? s[tid - off] : 0;
        __syncthreads();
        s[tid] += t;
        __syncthreads();
    }
    if (tid < nb) boff[tid] = s[tid] - v;   // exclusive
    if (tid == 255) rowptr[N] = s[255];
}

// Phase 3: block-local exclusive scan + block offset -> rowptr, pos
__global__ __launch_bounds__(256) void scan_blk_k(const int* __restrict__ cnt,
                                                  const int* __restrict__ boff,
                                                  int* __restrict__ rowptr,
                                                  int* __restrict__ pos, int N) {
    __shared__ int s[256];
    int tid = threadIdx.x;
    int i = blockIdx.x * 256 + tid;
    int v = (i < N) ? cnt[i] : 0;
    s[tid] = v;
    __syncthreads();
    #pragma unroll
    for (int off = 1; off < 256; off <<= 1) {
        int t = (tid >= off) ? s[tid - off] : 0;
        __syncthreads();
        s[tid] += t;
        __syncthreads();
    }
    int excl = s[tid] - v + boff[blockIdx.x];
    if (i < N) { rowptr[i] = excl; pos[i] = excl; }
}

// Counting-sort scatter: adj[slot] = src, bucketed by dst (int atomics only)
__global__ void fill_adj_k(const int* __restrict__ src, const int* __restrict__ dst,
                           int* __restrict__ pos, int* __restrict__ adj, int E) {
    int e = blockIdx.x * blockDim.x + threadIdx.x;
    if (e < E) {
        int slot = atomicAdd(&pos[dst[e]], 1);
        adj[slot] = src[e];
    }
}

// Pull-mean aggregation, D=128: one wave per node, lane owns float2.
__global__ __launch_bounds__(256) void gather_mean128_k(
        const float* __restrict__ X, const int* __restrict__ rowptr,
        const int* __restrict__ adj, float* __restrict__ out, int N) {
    int gw = (blockIdx.x * blockDim.x + threadIdx.x) >> 6;   // global wave = node
    int lane = threadIdx.x & 63;
    if (gw >= N) return;
    int beg = rowptr[gw], end = rowptr[gw + 1];
    const float2* X2 = (const float2*)X;
    float sx = 0.f, sy = 0.f;
    int n = beg;
    for (; n + 4 <= end; n += 4) {
        int s0 = adj[n], s1 = adj[n + 1], s2 = adj[n + 2], s3 = adj[n + 3];
        float2 v0 = X2[(size_t)s0 * 64 + lane];
        float2 v1 = X2[(size_t)s1 * 64 + lane];
        float2 v2 = X2[(size_t)s2 * 64 + lane];
        float2 v3 = X2[(size_t)s3 * 64 + lane];
        sx += v0.x + v1.x + v2.x + v3.x;
        sy += v0.y + v1.y + v2.y + v3.y;
    }
    for (; n < end; n++) {
        float2 v = X2[(size_t)adj[n] * 64 + lane];
        sx += v.x; sy += v.y;
    }
    int deg = end - beg;
    float inv = 1.0f / (float)(deg > 0 ? deg : 1);
    float2 o; o.x = sx * inv; o.y = sy * inv;
    ((float2*)out)[(size_t)gw * 64 + lane] = o;
}

// ---------------------------------------------------------------------------
// Split-bf16 MFMA fused GEMM:
//   out[r,c] = act( A1[r,:]·B1[c,:] + A2[r,:]·B2[c,:] + add[r,c] + bias[c] )
// fp32 inputs converted to bf16 hi+lo during LDS staging; 3 MFMAs per site
// (Ah·Bh + Ah·Bl + Al·Bh) ~= fp32 accuracy. 128x128 tile, BK=32, 4 waves,
// each wave 64x64 via 4x4 grid of 16x16x32 mfma.
#define TM 128
#define TN 128
#define TK 32
#define LSTR 40   // LDS row stride in shorts (32 data + 8 pad; 80B, 16B-aligned)

template <bool TANH, bool HAS_ADD>
__global__ __launch_bounds__(256)
void gemm_mfma_k(const float* __restrict__ A1, const float* __restrict__ B1, int K1,
                 const float* __restrict__ A2, const float* __restrict__ B2, int K2,
                 const float* __restrict__ add, const float* __restrict__ bias,
                 float* __restrict__ out, int N, int Md) {
    __shared__ short Ah[TM][LSTR], Al[TM][LSTR];
    __shared__ short Bh[TN][LSTR], Bl[TN][LSTR];

    const int tid = threadIdx.x;
    const int lane = tid & 63;
    const int wave = tid >> 6;              // 0..3
    const int waveM = (wave & 1) * 64;
    const int waveN = (wave >> 1) * 64;
    const int rowBase = blockIdx.x * TM;
    const int colBase = blockIdx.y * TN;

    f32x4 acc[4][4] = {{0.f, 0.f, 0.f, 0.f}};

    const int srow = tid >> 3;              // 0..31 (staging row group)
    const int scol = (tid & 7) * 4;         // float4 column within 32-wide k-chunk

    for (int k0 = 0; k0 < K1 + K2; k0 += TK) {
        const float* Ap; const float* Bp; int ko, ld;
        if (k0 < K1) { Ap = A1; Bp = B1; ko = k0;      ld = K1; }
        else         { Ap = A2; Bp = B2; ko = k0 - K1; ld = K2; }

        // Stage 128x32 A and B tiles as bf16 hi/lo (4 rows per thread, 32 apart)
        #pragma unroll
        for (int i = 0; i < 4; i++) {
            int r = srow + 32 * i;
            // A (bounds-checked rows)
            float4 av = make_float4(0.f, 0.f, 0.f, 0.f);
            int gr = rowBase + r;
            if (gr < N) av = *(const float4*)(Ap + (size_t)gr * ld + ko + scol);
            short4v ah, al;
            short2 p;
            p = split2(av.x); ah.x = p.x; al.x = p.y;
            p = split2(av.y); ah.y = p.x; al.y = p.y;
            p = split2(av.z); ah.z = p.x; al.z = p.y;
            p = split2(av.w); ah.w = p.x; al.w = p.y;
            *(short4v*)&Ah[r][scol] = ah;
            *(short4v*)&Al[r][scol] = al;
            // B (grid exact in cols)
            float4 bv = *(const float4*)(Bp + (size_t)(colBase + r) * ld + ko + scol);
            short4v bh, bl;
            p = split2(bv.x); bh.x = p.x; bl.x = p.y;
            p = split2(bv.y); bh.y = p.x; bl.y = p.y;
            p = split2(bv.z); bh.z = p.x; bl.z = p.y;
            p = split2(bv.w); bh.w = p.x; bl.w = p.y;
            *(short4v*)&Bh[r][scol] = bh;
            *(short4v*)&Bl[r][scol] = bl;
        }
        __syncthreads();

        // Fragments: A[m = lane&15][k = (lane>>4)*8 + j]
        const int fm = lane & 15;
        const int fq = (lane >> 4) * 8;
        short8 fah[4], fal[4], fbh[4], fbl[4];
        #pragma unroll
        for (int mi = 0; mi < 4; mi++) {
            fah[mi] = *(const short8*)&Ah[waveM + mi * 16 + fm][fq];
            fal[mi] = *(const short8*)&Al[waveM + mi * 16 + fm][fq];
        }
        #pragma unroll
        for (int ni = 0; ni < 4; ni++) {
            fbh[ni] = *(const short8*)&Bh[waveN + ni * 16 + fm][fq];
            fbl[ni] = *(const short8*)&Bl[waveN + ni * 16 + fm][fq];
        }

        #pragma unroll
        for (int mi = 0; mi < 4; mi++)
            #pragma unroll
            for (int ni = 0; ni < 4; ni++) {
                acc[mi][ni] = __builtin_amdgcn_mfma_f32_16x16x32_bf16(
                    fah[mi], fbh[ni], acc[mi][ni], 0, 0, 0);
                acc[mi][ni] = __builtin_amdgcn_mfma_f32_16x16x32_bf16(
                    fah[mi], fbl[ni], acc[mi][ni], 0, 0, 0);
                acc[mi][ni] = __builtin_amdgcn_mfma_f32_16x16x32_bf16(
                    fal[mi], fbh[ni], acc[mi][ni], 0, 0, 0);
            }
        __syncthreads();
    }

    // Epilogue. C/D layout (16x16): col = lane&15, row = (lane>>4)*4 + reg.
    const int orow0 = rowBase + waveM + (lane >> 4) * 4;
    const int ocol0 = colBase + waveN + (lane & 15);
    #pragma unroll
    for (int ni = 0; ni < 4; ni++) {
        int col = ocol0 + ni * 16;
        float bv = bias ? bias[col] : 0.0f;
        #pragma unroll
        for (int mi = 0; mi < 4; mi++) {
            #pragma unroll
            for (int r = 0; r < 4; r++) {
                int row = orow0 + mi * 16 + r;
                if (row >= N) continue;
                float v = acc[mi][ni][r] + bv;
                if (HAS_ADD) v += add[(size_t)row * Md + col];
                if (TANH) v = fast_tanh(v);
                out[(size_t)row * Md + col] = v;
            }
        }
    }
}

// ---------------------------------------------------------------------------
extern "C" void kernel_launch(void* const* d_in, const int* in_sizes, int n_in,
                              void* d_out, int out_size, void* d_ws, size_t ws_size,
                              hipStream_t stream) {
    const int N = N_NODES, E = N_EDGES;

    const float* x[2]   = {(const float*)d_in[0],  (const float*)d_in[1]};
    const int*   ei[2]  = {(const int*)d_in[2],    (const int*)d_in[3]};
    const float* W1l[2] = {(const float*)d_in[4],  (const float*)d_in[10]};
    const float* b1[2]  = {(const float*)d_in[5],  (const float*)d_in[11]};
    const float* W1r[2] = {(const float*)d_in[6],  (const float*)d_in[12]};
    const float* W2l[2] = {(const float*)d_in[7],  (const float*)d_in[13]};
    const float* b2[2]  = {(const float*)d_in[8],  (const float*)d_in[14]};
    const float* W2r[2] = {(const float*)d_in[9],  (const float*)d_in[15]};
    float* out = (float*)d_out;

    // Workspace layout (reused across both graphs):
    //   cnt    [0,      256K)   N ints
    //   rowptr [256K,   512K)   N+1 ints
    //   pos    [512K,   768K)   N ints
    //   bsum   [768K,   +1K)    SCAN_NB ints
    //   boff   [769K,   +1K)    SCAN_NB ints
    //   adj    [1M,     +3.2M)  E ints
    //   bufA   [8M,     +25.6M) N x 128 f32 : mean1, later z
    //   bufB   [+,      +25.6M) N x 128 f32 : aggz
    //   h      [+,      +51.2M) N x 256 f32
    char* wsb = (char*)d_ws;
    int*   cnt    = (int*)(wsb);
    int*   rowptr = (int*)(wsb + (256 << 10));
    int*   pos    = (int*)(wsb + (512 << 10));
    int*   bsum   = (int*)(wsb + (768 << 10));
    int*   boff   = (int*)(wsb + (769 << 10));
    int*   adj    = (int*)(wsb + (1 << 20));
    float* bufA   = (float*)(wsb + (8 << 20));
    float* bufB   = (float*)(wsb + (8 << 20) + (size_t)N * 128 * sizeof(float));
    float* h      = (float*)(wsb + (8 << 20) + 2 * (size_t)N * 128 * sizeof(float));

    const int gemm_rows = (N + TM - 1) / TM;      // 391
    const int agg_blocks = (N * 64 + 255) / 256;  // wave-per-node

    for (int g = 0; g < 2; g++) {
        const int* src = ei[g];
        const int* dst = ei[g] + E;

        // ---- CSR build (counting sort by dst); grid scan
        (void)hipMemsetAsync(cnt, 0, (size_t)N * sizeof(int), stream);
        count_k<<<(E + 255) / 256, 256, 0, stream>>>(dst, cnt, E);
        bsum_k<<<SCAN_NB, 256, 0, stream>>>(cnt, bsum, N);
        boff_k<<<1, 256, 0, stream>>>(bsum, boff, rowptr, SCAN_NB, N);
        scan_blk_k<<<SCAN_NB, 256, 0, stream>>>(cnt, boff, rowptr, pos, N);
        fill_adj_k<<<(E + 255) / 256, 256, 0, stream>>>(src, dst, pos, adj, E);

        // ---- Layer 1: mean1 = mean-agg(x) [D=128]
        gather_mean128_k<<<agg_blocks, 256, 0, stream>>>(x[g], rowptr, adj, bufA, N);
        // h = tanh(mean1@W1l^T + x@W1r^T + b1)   [K=128+128 -> 256]
        gemm_mfma_k<true, false><<<dim3(gemm_rows, 256 / TN), 256, 0, stream>>>(
            bufA, W1l[g], 128, x[g], W1r[g], 128, nullptr, b1[g], h, N, 256);

        // ---- Layer 2 (linearity): z = h@W2l^T first, then aggregate z
        gemm_mfma_k<false, false><<<dim3(gemm_rows, 128 / TN), 256, 0, stream>>>(
            h, W2l[g], 256, nullptr, nullptr, 0, nullptr, nullptr, bufA, N, 128);
        // aggz = mean-agg(z) [D=128]
        gather_mean128_k<<<agg_blocks, 256, 0, stream>>>(bufA, rowptr, adj, bufB, N);
        // out = tanh(aggz + h@W2r^T + b2)   [K=256 -> 128]
        gemm_mfma_k<true, true><<<dim3(gemm_rows, 128 / TN), 256, 0, stream>>>(
            h, W2r[g], 256, nullptr, nullptr, 0, bufB, b2[g],
            out + (size_t)g * N * 128, N, 128);
    }
}

// Round 6
// 753.393 us; speedup vs baseline: 11.9592x; 1.1068x over previous
//
#include <hip/hip_runtime.h>
#include <cstddef>

// Problem constants (from reference setup_inputs)
#define N_NODES 50000
#define N_EDGES 800000

typedef __attribute__((ext_vector_type(8))) short short8;   // 8 bf16 (4 VGPRs)
typedef __attribute__((ext_vector_type(4))) short short4v;  // 4 bf16
typedef __attribute__((ext_vector_type(4))) float f32x4;    // MFMA acc

// ---------------------------------------------------------------------------
// fast tanh via v_exp_f32; abs err ~1e-7, threshold is 2e-2.
__device__ __forceinline__ float fast_tanh(float x) {
    float t = __expf(2.0f * x);
    return 1.0f - 2.0f / (t + 1.0f);
}

// round-to-nearest-even f32 -> bf16 bit pattern
__device__ __forceinline__ short bf16_rne(float x) {
    unsigned u = __float_as_uint(x);
    unsigned r = u + 0x7FFFu + ((u >> 16) & 1u);
    return (short)(r >> 16);
}
// split x ~= hi + lo (both bf16); hi rounded RNE, lo = bf16(x - hi).
__device__ __forceinline__ short2 split2(float x) {
    unsigned u = __float_as_uint(x);
    unsigned r = (u + 0x7FFFu + ((u >> 16) & 1u)) & 0xFFFF0000u;
    short2 p;
    p.x = (short)(r >> 16);
    p.y = bf16_rne(x - __uint_as_float(r));
    return p;
}

// Convert f32 array -> split bf16 hi/lo arrays. One float4 per thread.
__global__ void convert_split_k(const float* __restrict__ src, short* __restrict__ h,
                                short* __restrict__ l, int n4) {
    int i = blockIdx.x * blockDim.x + threadIdx.x;
    if (i >= n4) return;
    float4 v = ((const float4*)src)[i];
    short4v hs, ls; short2 p;
    p = split2(v.x); hs.x = p.x; ls.x = p.y;
    p = split2(v.y); hs.y = p.x; ls.y = p.y;
    p = split2(v.z); hs.z = p.x; ls.z = p.y;
    p = split2(v.w); hs.w = p.x; ls.w = p.y;
    ((short4v*)h)[i] = hs;
    ((short4v*)l)[i] = ls;
}

// ---------------------------------------------------------------------------
// Degree count: cnt[dst]++ per edge (int atomics)
__global__ void count_k(const int* __restrict__ dst, int* __restrict__ cnt, int E) {
    int e = blockIdx.x * blockDim.x + threadIdx.x;
    if (e < E) atomicAdd(&cnt[dst[e]], 1);
}

// ---- 3-phase grid scan -----------------------------------------------------
#define SCAN_NB ((N_NODES + 255) / 256)   // 196 blocks

__global__ __launch_bounds__(256) void bsum_k(const int* __restrict__ cnt,
                                              int* __restrict__ bsum, int N) {
    __shared__ int red[256];
    int i = blockIdx.x * 256 + threadIdx.x;
    int v = (i < N) ? cnt[i] : 0;
    red[threadIdx.x] = v;
    __syncthreads();
    #pragma unroll
    for (int off = 128; off > 0; off >>= 1) {
        if (threadIdx.x < off) red[threadIdx.x] += red[threadIdx.x + off];
        __syncthreads();
    }
    if (threadIdx.x == 0) bsum[blockIdx.x] = red[0];
}

__global__ __launch_bounds__(256) void boff_k(const int* __restrict__ bsum,
                                              int* __restrict__ boff,
                                              int* __restrict__ rowptr,
                                              int nb, int N) {
    __shared__ int s[256];
    int tid = threadIdx.x;
    int v = (tid < nb) ? bsum[tid] : 0;
    s[tid] = v;
    __syncthreads();
    #pragma unroll
    for (int off = 1; off < 256; off <<= 1) {
        int t = (tid >= off) ? s[tid - off] : 0;
        __syncthreads();
        s[tid] += t;
        __syncthreads();
    }
    if (tid < nb) boff[tid] = s[tid] - v;   // exclusive
    if (tid == 255) rowptr[N] = s[255];
}

__global__ __launch_bounds__(256) void scan_blk_k(const int* __restrict__ cnt,
                                                  const int* __restrict__ boff,
                                                  int* __restrict__ rowptr,
                                                  int* __restrict__ pos, int N) {
    __shared__ int s[256];
    int tid = threadIdx.x;
    int i = blockIdx.x * 256 + tid;
    int v = (i < N) ? cnt[i] : 0;
    s[tid] = v;
    __syncthreads();
    #pragma unroll
    for (int off = 1; off < 256; off <<= 1) {
        int t = (tid >= off) ? s[tid - off] : 0;
        __syncthreads();
        s[tid] += t;
        __syncthreads();
    }
    int excl = s[tid] - v + boff[blockIdx.x];
    if (i < N) { rowptr[i] = excl; pos[i] = excl; }
}

// Counting-sort scatter: adj[slot] = src, bucketed by dst (int atomics only)
__global__ void fill_adj_k(const int* __restrict__ src, const int* __restrict__ dst,
                           int* __restrict__ pos, int* __restrict__ adj, int E) {
    int e = blockIdx.x * blockDim.x + threadIdx.x;
    if (e < E) {
        int slot = atomicAdd(&pos[dst[e]], 1);
        adj[slot] = src[e];
    }
}

// ---------------------------------------------------------------------------
// Pull-mean aggregation over bf16 rows (D=128, 256B/row): one wave per node,
// lane owns one uint = 2 bf16. f32 accumulate.
// OUTM 0: split bf16 hi/lo outputs (packed 2/uint). OUTM 1: f32 output.
template <int OUTM>
__global__ __launch_bounds__(256) void gather_mean_k(
        const unsigned* __restrict__ X2,   // bf16 [N][128] viewed as [N][64] uints
        const int* __restrict__ rowptr, const int* __restrict__ adj,
        unsigned* __restrict__ outh, unsigned* __restrict__ outl,
        float* __restrict__ outf, int N) {
    int gw = (blockIdx.x * blockDim.x + threadIdx.x) >> 6;   // node
    int lane = threadIdx.x & 63;
    if (gw >= N) return;
    int beg = rowptr[gw], end = rowptr[gw + 1];
    float sx = 0.f, sy = 0.f;
    int n = beg;
    for (; n + 4 <= end; n += 4) {
        unsigned u0 = X2[(size_t)adj[n] * 64 + lane];
        unsigned u1 = X2[(size_t)adj[n + 1] * 64 + lane];
        unsigned u2 = X2[(size_t)adj[n + 2] * 64 + lane];
        unsigned u3 = X2[(size_t)adj[n + 3] * 64 + lane];
        sx += __uint_as_float(u0 << 16) + __uint_as_float(u1 << 16)
            + __uint_as_float(u2 << 16) + __uint_as_float(u3 << 16);
        sy += __uint_as_float(u0 & 0xFFFF0000u) + __uint_as_float(u1 & 0xFFFF0000u)
            + __uint_as_float(u2 & 0xFFFF0000u) + __uint_as_float(u3 & 0xFFFF0000u);
    }
    for (; n < end; n++) {
        unsigned u = X2[(size_t)adj[n] * 64 + lane];
        sx += __uint_as_float(u << 16);
        sy += __uint_as_float(u & 0xFFFF0000u);
    }
    int deg = end - beg;
    float inv = 1.0f / (float)(deg > 0 ? deg : 1);
    float mx = sx * inv, my = sy * inv;
    if (OUTM == 0) {
        short2 px = split2(mx), py = split2(my);
        outh[(size_t)gw * 64 + lane] =
            (unsigned)(unsigned short)px.x | ((unsigned)(unsigned short)py.x << 16);
        outl[(size_t)gw * 64 + lane] =
            (unsigned)(unsigned short)px.y | ((unsigned)(unsigned short)py.y << 16);
    } else {
        float2 o; o.x = mx; o.y = my;
        ((float2*)outf)[(size_t)gw * 64 + lane] = o;
    }
}

// ---------------------------------------------------------------------------
// Split-bf16 MFMA fused GEMM, operands PRE-SPLIT in global memory:
//   out[r,c] = act( A1[r,:]·B1[c,:] + A2[r,:]·B2[c,:] + add[r,c] + bias[c] )
// 3 MFMAs per site (Ah·Bh + Ah·Bl + Al·Bh) ~= fp32. 128x64 tile, BK=32,
// 4 waves in 2x2, each wave 64x32 via 4x2 grid of 16x16x32 mfma.
// EMIT: 0 = f32 out, 1 = bf16-hi out, 2 = split bf16 hi+lo out.
#define TM 128
#define TN 64
#define TK 32
#define LSTR 40   // LDS row stride in shorts (32 data + 8 pad; 80B, 16B-aligned)

template <int EMIT, bool TANH, bool HAS_ADD>
__global__ __launch_bounds__(256)
void gemm_bf16s_k(const short* __restrict__ A1h, const short* __restrict__ A1l,
                  const short* __restrict__ B1h, const short* __restrict__ B1l, int K1,
                  const short* __restrict__ A2h, const short* __restrict__ A2l,
                  const short* __restrict__ B2h, const short* __restrict__ B2l, int K2,
                  const float* __restrict__ add, const float* __restrict__ bias,
                  float* __restrict__ outf, short* __restrict__ outh,
                  short* __restrict__ outl, int N, int Md) {
    __shared__ short sAh[TM][LSTR], sAl[TM][LSTR];
    __shared__ short sBh[TN][LSTR], sBl[TN][LSTR];

    const int tid = threadIdx.x;
    const int lane = tid & 63;
    const int wave = tid >> 6;              // 0..3
    const int waveM = (wave & 1) * 64;
    const int waveN = (wave >> 1) * 32;
    const int rowBase = blockIdx.x * TM;
    const int colBase = blockIdx.y * TN;

    f32x4 acc[4][2] = {};

    for (int k0 = 0; k0 < K1 + K2; k0 += TK) {
        const short *Ah, *Al, *Bh, *Bl; int ko, ld;
        if (k0 < K1) { Ah = A1h; Al = A1l; Bh = B1h; Bl = B1l; ko = k0;      ld = K1; }
        else         { Ah = A2h; Al = A2l; Bh = B2h; Bl = B2l; ko = k0 - K1; ld = K2; }

        // Stage A: 128 rows x 32 bf16 = 512 16B-chunks; 2 per thread (h and l).
        #pragma unroll
        for (int i = 0; i < 2; i++) {
            int chunk = tid + i * 256;
            int r = chunk >> 2, c = chunk & 3;
            int gr = rowBase + r;
            short8 vh = {0,0,0,0,0,0,0,0}, vl = {0,0,0,0,0,0,0,0};
            if (gr < N) {
                size_t off = (size_t)gr * ld + ko + c * 8;
                vh = *(const short8*)(Ah + off);
                vl = *(const short8*)(Al + off);
            }
            *(short8*)&sAh[r][c * 8] = vh;
            *(short8*)&sAl[r][c * 8] = vl;
        }
        // Stage B: 64 rows x 32 bf16 = 256 chunks; 1 per thread (h and l).
        {
            int r = tid >> 2, c = tid & 3;
            size_t off = (size_t)(colBase + r) * ld + ko + c * 8;
            *(short8*)&sBh[r][c * 8] = *(const short8*)(Bh + off);
            *(short8*)&sBl[r][c * 8] = *(const short8*)(Bl + off);
        }
        __syncthreads();

        // Fragments: A[m = lane&15][k = (lane>>4)*8 + j]
        const int fm = lane & 15;
        const int fq = (lane >> 4) * 8;
        short8 fah[4], fal[4], fbh[2], fbl[2];
        #pragma unroll
        for (int mi = 0; mi < 4; mi++) {
            fah[mi] = *(const short8*)&sAh[waveM + mi * 16 + fm][fq];
            fal[mi] = *(const short8*)&sAl[waveM + mi * 16 + fm][fq];
        }
        #pragma unroll
        for (int ni = 0; ni < 2; ni++) {
            fbh[ni] = *(const short8*)&sBh[waveN + ni * 16 + fm][fq];
            fbl[ni] = *(const short8*)&sBl[waveN + ni * 16 + fm][fq];
        }

        #pragma unroll
        for (int mi = 0; mi < 4; mi++)
            #pragma unroll
            for (int ni = 0; ni < 2; ni++) {
                acc[mi][ni] = __builtin_amdgcn_mfma_f32_16x16x32_bf16(
                    fah[mi], fbh[ni], acc[mi][ni], 0, 0, 0);
                acc[mi][ni] = __builtin_amdgcn_mfma_f32_16x16x32_bf16(
                    fah[mi], fbl[ni], acc[mi][ni], 0, 0, 0);
                acc[mi][ni] = __builtin_amdgcn_mfma_f32_16x16x32_bf16(
                    fal[mi], fbh[ni], acc[mi][ni], 0, 0, 0);
            }
        __syncthreads();
    }

    // Epilogue. C/D layout (16x16): col = lane&15, row = (lane>>4)*4 + reg.
    const int orow0 = rowBase + waveM + (lane >> 4) * 4;
    const int ocol0 = colBase + waveN + (lane & 15);
    #pragma unroll
    for (int ni = 0; ni < 2; ni++) {
        int col = ocol0 + ni * 16;
        float bv = bias ? bias[col] : 0.0f;
        #pragma unroll
        for (int mi = 0; mi < 4; mi++) {
            #pragma unroll
            for (int r = 0; r < 4; r++) {
                int row = orow0 + mi * 16 + r;
                if (row >= N) continue;
                float v = acc[mi][ni][r] + bv;
                if (HAS_ADD) v += add[(size_t)row * Md + col];
                if (TANH) v = fast_tanh(v);
                size_t oidx = (size_t)row * Md + col;
                if (EMIT == 0) outf[oidx] = v;
                else if (EMIT == 1) outh[oidx] = bf16_rne(v);
                else { short2 p = split2(v); outh[oidx] = p.x; outl[oidx] = p.y; }
            }
        }
    }
}

// ---------------------------------------------------------------------------
extern "C" void kernel_launch(void* const* d_in, const int* in_sizes, int n_in,
                              void* d_out, int out_size, void* d_ws, size_t ws_size,
                              hipStream_t stream) {
    const int N = N_NODES, E = N_EDGES;

    const float* x[2]   = {(const float*)d_in[0],  (const float*)d_in[1]};
    const int*   ei[2]  = {(const int*)d_in[2],    (const int*)d_in[3]};
    const float* W1l[2] = {(const float*)d_in[4],  (const float*)d_in[10]};
    const float* b1[2]  = {(const float*)d_in[5],  (const float*)d_in[11]};
    const float* W1r[2] = {(const float*)d_in[6],  (const float*)d_in[12]};
    const float* W2l[2] = {(const float*)d_in[7],  (const float*)d_in[13]};
    const float* b2[2]  = {(const float*)d_in[8],  (const float*)d_in[14]};
    const float* W2r[2] = {(const float*)d_in[9],  (const float*)d_in[15]};
    float* out = (float*)d_out;

    // Workspace layout (MiB offsets; all buffers reused across the 2 graphs):
    //   cnt@0 rowptr@256K pos@512K bsum@768K boff@769K adj@1MiB(3.05MiB)
    //   weights(split)@4.25MiB (8 x 64KiB)
    //   xh@5  xl@18  meanh@31 meanl@44  hh@57 hl@82   [MiB]
    //   zh aliases xh@5; aggz(f32) aliases mean@31 (both dead by then)
    char* wsb = (char*)d_ws;
    const size_t MiB = 1u << 20;
    int*   cnt    = (int*)(wsb);
    int*   rowptr = (int*)(wsb + 256 * 1024);
    int*   pos    = (int*)(wsb + 512 * 1024);
    int*   bsum   = (int*)(wsb + 768 * 1024);
    int*   boff   = (int*)(wsb + 769 * 1024);
    int*   adj    = (int*)(wsb + 1 * MiB);
    short* Wbuf   = (short*)(wsb + 4 * MiB + 256 * 1024);
    short* W1lh = Wbuf;          short* W1ll = Wbuf + 32768;
    short* W1rh = Wbuf + 65536;  short* W1rl = Wbuf + 98304;
    short* W2lh = Wbuf + 131072; short* W2ll = Wbuf + 163840;
    short* W2rh = Wbuf + 196608; short* W2rl = Wbuf + 229376;
    short* xh    = (short*)(wsb + 5 * MiB);
    short* xl    = (short*)(wsb + 18 * MiB);
    short* meanh = (short*)(wsb + 31 * MiB);
    short* meanl = (short*)(wsb + 44 * MiB);
    short* hh    = (short*)(wsb + 57 * MiB);
    short* hl    = (short*)(wsb + 82 * MiB);
    short* zh    = xh;                       // alias (x dead after L1 GEMM)
    float* aggz  = (float*)(wsb + 31 * MiB); // alias (mean dead after L1 GEMM)

    const int gemm_rows = (N + TM - 1) / TM;      // 391
    const int agg_blocks = (N * 64 + 255) / 256;  // wave-per-node

    for (int g = 0; g < 2; g++) {
        const int* src = ei[g];
        const int* dst = ei[g] + E;

        // ---- CSR build (counting sort by dst); grid scan
        (void)hipMemsetAsync(cnt, 0, (size_t)N * sizeof(int), stream);
        count_k<<<(E + 255) / 256, 256, 0, stream>>>(dst, cnt, E);
        bsum_k<<<SCAN_NB, 256, 0, stream>>>(cnt, bsum, N);
        boff_k<<<1, 256, 0, stream>>>(bsum, boff, rowptr, SCAN_NB, N);
        scan_blk_k<<<SCAN_NB, 256, 0, stream>>>(cnt, boff, rowptr, pos, N);
        fill_adj_k<<<(E + 255) / 256, 256, 0, stream>>>(src, dst, pos, adj, E);

        // ---- Pre-split x and weights to bf16 hi/lo
        convert_split_k<<<(N * 32 + 255) / 256, 256, 0, stream>>>(x[g], xh, xl, N * 32);
        convert_split_k<<<32, 256, 0, stream>>>(W1l[g], W1lh, W1ll, 8192);
        convert_split_k<<<32, 256, 0, stream>>>(W1r[g], W1rh, W1rl, 8192);
        convert_split_k<<<32, 256, 0, stream>>>(W2l[g], W2lh, W2ll, 8192);
        convert_split_k<<<32, 256, 0, stream>>>(W2r[g], W2rh, W2rl, 8192);

        // ---- Layer 1: mean1 = mean-agg(x_bf16) -> split bf16
        gather_mean_k<0><<<agg_blocks, 256, 0, stream>>>(
            (const unsigned*)xh, rowptr, adj, (unsigned*)meanh, (unsigned*)meanl,
            nullptr, N);
        // h = tanh(mean1@W1l^T + x@W1r^T + b1) -> split bf16 hh/hl  [K=256 -> 256]
        gemm_bf16s_k<2, true, false><<<dim3(gemm_rows, 256 / TN), 256, 0, stream>>>(
            meanh, meanl, W1lh, W1ll, 128, xh, xl, W1rh, W1rl, 128,
            nullptr, b1[g], nullptr, hh, hl, N, 256);

        // ---- Layer 2 (linearity): z = h@W2l^T -> bf16 hi only
        gemm_bf16s_k<1, false, false><<<dim3(gemm_rows, 128 / TN), 256, 0, stream>>>(
            hh, hl, W2lh, W2ll, 256, nullptr, nullptr, nullptr, nullptr, 0,
            nullptr, nullptr, nullptr, zh, nullptr, N, 128);
        // aggz = mean-agg(z_bf16) -> f32
        gather_mean_k<1><<<agg_blocks, 256, 0, stream>>>(
            (const unsigned*)zh, rowptr, adj, nullptr, nullptr, aggz, N);
        // out = tanh(aggz + h@W2r^T + b2) -> f32  [K=256 -> 128]
        gemm_bf16s_k<0, true, true><<<dim3(gemm_rows, 128 / TN), 256, 0, stream>>>(
            hh, hl, W2rh, W2rl, 256, nullptr, nullptr, nullptr, nullptr, 0,
            aggz, b2[g], out + (size_t)g * N * 128, nullptr, nullptr, N, 128);
    }
}

// Round 7
// 733.658 us; speedup vs baseline: 12.2809x; 1.0269x over previous
//
#include <hip/hip_runtime.h>
#include <cstddef>

// Problem constants (from reference setup_inputs)
#define N_NODES 50000
#define N_EDGES 800000

typedef __attribute__((ext_vector_type(8))) short short8;   // 8 bf16 (4 VGPRs)
typedef __attribute__((ext_vector_type(4))) short short4v;  // 4 bf16
typedef __attribute__((ext_vector_type(4))) float f32x4;    // MFMA acc

// ---------------------------------------------------------------------------
// fast tanh via v_exp_f32; abs err ~1e-7, threshold is 2e-2.
__device__ __forceinline__ float fast_tanh(float x) {
    float t = __expf(2.0f * x);
    return 1.0f - 2.0f / (t + 1.0f);
}

// round-to-nearest-even f32 -> bf16 bit pattern
__device__ __forceinline__ short bf16_rne(float x) {
    unsigned u = __float_as_uint(x);
    unsigned r = u + 0x7FFFu + ((u >> 16) & 1u);
    return (short)(r >> 16);
}
// split x ~= hi + lo (both bf16); hi rounded RNE, lo = bf16(x - hi).
__device__ __forceinline__ short2 split2(float x) {
    unsigned u = __float_as_uint(x);
    unsigned r = (u + 0x7FFFu + ((u >> 16) & 1u)) & 0xFFFF0000u;
    short2 p;
    p.x = (short)(r >> 16);
    p.y = bf16_rne(x - __uint_as_float(r));
    return p;
}

// Convert f32 array -> split bf16 hi/lo arrays. One float4 per thread.
__global__ void convert_split_k(const float* __restrict__ src, short* __restrict__ h,
                                short* __restrict__ l, int n4) {
    int i = blockIdx.x * blockDim.x + threadIdx.x;
    if (i >= n4) return;
    float4 v = ((const float4*)src)[i];
    short4v hs, ls; short2 p;
    p = split2(v.x); hs.x = p.x; ls.x = p.y;
    p = split2(v.y); hs.y = p.x; ls.y = p.y;
    p = split2(v.z); hs.z = p.x; ls.z = p.y;
    p = split2(v.w); hs.w = p.x; ls.w = p.y;
    ((short4v*)h)[i] = hs;
    ((short4v*)l)[i] = ls;
}

// ---------------------------------------------------------------------------
// Degree count: cnt[dst]++ per edge (int atomics)
__global__ void count_k(const int* __restrict__ dst, int* __restrict__ cnt, int E) {
    int e = blockIdx.x * blockDim.x + threadIdx.x;
    if (e < E) atomicAdd(&cnt[dst[e]], 1);
}

// ---- 3-phase grid scan -----------------------------------------------------
#define SCAN_NB ((N_NODES + 255) / 256)   // 196 blocks

__global__ __launch_bounds__(256) void bsum_k(const int* __restrict__ cnt,
                                              int* __restrict__ bsum, int N) {
    __shared__ int red[256];
    int i = blockIdx.x * 256 + threadIdx.x;
    int v = (i < N) ? cnt[i] : 0;
    red[threadIdx.x] = v;
    __syncthreads();
    #pragma unroll
    for (int off = 128; off > 0; off >>= 1) {
        if (threadIdx.x < off) red[threadIdx.x] += red[threadIdx.x + off];
        __syncthreads();
    }
    if (threadIdx.x == 0) bsum[blockIdx.x] = red[0];
}

__global__ __launch_bounds__(256) void boff_k(const int* __restrict__ bsum,
                                              int* __restrict__ boff,
                                              int* __restrict__ rowptr,
                                              int nb, int N) {
    __shared__ int s[256];
    int tid = threadIdx.x;
    int v = (tid < nb) ? bsum[tid] : 0;
    s[tid] = v;
    __syncthreads();
    #pragma unroll
    for (int off = 1; off < 256; off <<= 1) {
        int t = (tid >= off) ? s[tid - off] : 0;
        __syncthreads();
        s[tid] += t;
        __syncthreads();
    }
    if (tid < nb) boff[tid] = s[tid] - v;   // exclusive
    if (tid == 255) rowptr[N] = s[255];
}

__global__ __launch_bounds__(256) void scan_blk_k(const int* __restrict__ cnt,
                                                  const int* __restrict__ boff,
                                                  int* __restrict__ rowptr,
                                                  int* __restrict__ pos, int N) {
    __shared__ int s[256];
    int tid = threadIdx.x;
    int i = blockIdx.x * 256 + tid;
    int v = (i < N) ? cnt[i] : 0;
    s[tid] = v;
    __syncthreads();
    #pragma unroll
    for (int off = 1; off < 256; off <<= 1) {
        int t = (tid >= off) ? s[tid - off] : 0;
        __syncthreads();
        s[tid] += t;
        __syncthreads();
    }
    int excl = s[tid] - v + boff[blockIdx.x];
    if (i < N) { rowptr[i] = excl; pos[i] = excl; }
}

// Counting-sort scatter: adj[slot] = src, bucketed by dst (int atomics only)
__global__ void fill_adj_k(const int* __restrict__ src, const int* __restrict__ dst,
                           int* __restrict__ pos, int* __restrict__ adj, int E) {
    int e = blockIdx.x * blockDim.x + threadIdx.x;
    if (e < E) {
        int slot = atomicAdd(&pos[dst[e]], 1);
        adj[slot] = src[e];
    }
}

// ---------------------------------------------------------------------------
// Pull-mean aggregation over bf16 rows (D=128, 256B/row): one wave per node,
// lane owns one uint = 2 bf16. f32 accumulate.
// OUTM 0: split bf16 hi/lo outputs (packed 2/uint). OUTM 1: f32 output.
template <int OUTM>
__global__ __launch_bounds__(256) void gather_mean_k(
        const unsigned* __restrict__ X2,   // bf16 [N][128] viewed as [N][64] uints
        const int* __restrict__ rowptr, const int* __restrict__ adj,
        unsigned* __restrict__ outh, unsigned* __restrict__ outl,
        float* __restrict__ outf, int N) {
    int gw = (blockIdx.x * blockDim.x + threadIdx.x) >> 6;   // node
    int lane = threadIdx.x & 63;
    if (gw >= N) return;
    int beg = rowptr[gw], end = rowptr[gw + 1];
    float sx = 0.f, sy = 0.f;
    int n = beg;
    for (; n + 4 <= end; n += 4) {
        unsigned u0 = X2[(size_t)adj[n] * 64 + lane];
        unsigned u1 = X2[(size_t)adj[n + 1] * 64 + lane];
        unsigned u2 = X2[(size_t)adj[n + 2] * 64 + lane];
        unsigned u3 = X2[(size_t)adj[n + 3] * 64 + lane];
        sx += __uint_as_float(u0 << 16) + __uint_as_float(u1 << 16)
            + __uint_as_float(u2 << 16) + __uint_as_float(u3 << 16);
        sy += __uint_as_float(u0 & 0xFFFF0000u) + __uint_as_float(u1 & 0xFFFF0000u)
            + __uint_as_float(u2 & 0xFFFF0000u) + __uint_as_float(u3 & 0xFFFF0000u);
    }
    for (; n < end; n++) {
        unsigned u = X2[(size_t)adj[n] * 64 + lane];
        sx += __uint_as_float(u << 16);
        sy += __uint_as_float(u & 0xFFFF0000u);
    }
    int deg = end - beg;
    float inv = 1.0f / (float)(deg > 0 ? deg : 1);
    float mx = sx * inv, my = sy * inv;
    if (OUTM == 0) {
        short2 px = split2(mx), py = split2(my);
        outh[(size_t)gw * 64 + lane] =
            (unsigned)(unsigned short)px.x | ((unsigned)(unsigned short)py.x << 16);
        outl[(size_t)gw * 64 + lane] =
            (unsigned)(unsigned short)px.y | ((unsigned)(unsigned short)py.y << 16);
    } else {
        float2 o; o.x = mx; o.y = my;
        ((float2*)outf)[(size_t)gw * 64 + lane] = o;
    }
}

// ---------------------------------------------------------------------------
// Split-bf16 MFMA fused GEMM, operands PRE-SPLIT in global memory:
//   out[r,c] = act( A1[r,:]·B1[c,:] + A2[r,:]·B2[c,:] + add[r,c] + bias[c] )
// 3 MFMAs per site (Ah·Bh + Ah·Bl + Al·Bh) ~= fp32. 128x128 tile, BK=32,
// 4 waves in 2x2, each wave 64x64 via 4x4 grid of 16x16x32 mfma.
// Grid: (cols, rows) -- column index varies FASTEST so the column blocks
// sharing a row-tile dispatch adjacently (A-tile L2/L3 temporal reuse).
// EMIT: 0 = f32 out, 1 = bf16-hi out, 2 = split bf16 hi+lo out.
#define TM 128
#define TN 128
#define TK 32
#define LSTR 40   // LDS row stride in shorts (32 data + 8 pad; 80B, 16B-aligned)

template <int EMIT, bool TANH, bool HAS_ADD>
__global__ __launch_bounds__(256)
void gemm_bf16s_k(const short* __restrict__ A1h, const short* __restrict__ A1l,
                  const short* __restrict__ B1h, const short* __restrict__ B1l, int K1,
                  const short* __restrict__ A2h, const short* __restrict__ A2l,
                  const short* __restrict__ B2h, const short* __restrict__ B2l, int K2,
                  const float* __restrict__ add, const float* __restrict__ bias,
                  float* __restrict__ outf, short* __restrict__ outh,
                  short* __restrict__ outl, int N, int Md) {
    __shared__ short sAh[TM][LSTR], sAl[TM][LSTR];
    __shared__ short sBh[TN][LSTR], sBl[TN][LSTR];

    const int tid = threadIdx.x;
    const int lane = tid & 63;
    const int wave = tid >> 6;              // 0..3
    const int waveM = (wave & 1) * 64;
    const int waveN = (wave >> 1) * 64;
    const int rowBase = blockIdx.y * TM;
    const int colBase = blockIdx.x * TN;

    f32x4 acc[4][4] = {};

    for (int k0 = 0; k0 < K1 + K2; k0 += TK) {
        const short *Ah, *Al, *Bh, *Bl; int ko, ld;
        if (k0 < K1) { Ah = A1h; Al = A1l; Bh = B1h; Bl = B1l; ko = k0;      ld = K1; }
        else         { Ah = A2h; Al = A2l; Bh = B2h; Bl = B2l; ko = k0 - K1; ld = K2; }

        // Stage A and B: each 128 rows x 32 bf16 = 512 16B-chunks (h and l);
        // 2 chunk-pairs of each per thread.
        #pragma unroll
        for (int i = 0; i < 2; i++) {
            int chunk = tid + i * 256;
            int r = chunk >> 2, c = chunk & 3;
            int gr = rowBase + r;
            short8 vh = {0,0,0,0,0,0,0,0}, vl = {0,0,0,0,0,0,0,0};
            if (gr < N) {
                size_t off = (size_t)gr * ld + ko + c * 8;
                vh = *(const short8*)(Ah + off);
                vl = *(const short8*)(Al + off);
            }
            *(short8*)&sAh[r][c * 8] = vh;
            *(short8*)&sAl[r][c * 8] = vl;
            size_t boffs = (size_t)(colBase + r) * ld + ko + c * 8;
            *(short8*)&sBh[r][c * 8] = *(const short8*)(Bh + boffs);
            *(short8*)&sBl[r][c * 8] = *(const short8*)(Bl + boffs);
        }
        __syncthreads();

        // Fragments: A[m = lane&15][k = (lane>>4)*8 + j]
        const int fm = lane & 15;
        const int fq = (lane >> 4) * 8;
        short8 fah[4], fal[4], fbh[4], fbl[4];
        #pragma unroll
        for (int mi = 0; mi < 4; mi++) {
            fah[mi] = *(const short8*)&sAh[waveM + mi * 16 + fm][fq];
            fal[mi] = *(const short8*)&sAl[waveM + mi * 16 + fm][fq];
        }
        #pragma unroll
        for (int ni = 0; ni < 4; ni++) {
            fbh[ni] = *(const short8*)&sBh[waveN + ni * 16 + fm][fq];
            fbl[ni] = *(const short8*)&sBl[waveN + ni * 16 + fm][fq];
        }

        #pragma unroll
        for (int mi = 0; mi < 4; mi++)
            #pragma unroll
            for (int ni = 0; ni < 4; ni++) {
                acc[mi][ni] = __builtin_amdgcn_mfma_f32_16x16x32_bf16(
                    fah[mi], fbh[ni], acc[mi][ni], 0, 0, 0);
                acc[mi][ni] = __builtin_amdgcn_mfma_f32_16x16x32_bf16(
                    fah[mi], fbl[ni], acc[mi][ni], 0, 0, 0);
                acc[mi][ni] = __builtin_amdgcn_mfma_f32_16x16x32_bf16(
                    fal[mi], fbh[ni], acc[mi][ni], 0, 0, 0);
            }
        __syncthreads();
    }

    // Epilogue. C/D layout (16x16): col = lane&15, row = (lane>>4)*4 + reg.
    const int orow0 = rowBase + waveM + (lane >> 4) * 4;
    const int ocol0 = colBase + waveN + (lane & 15);
    #pragma unroll
    for (int ni = 0; ni < 4; ni++) {
        int col = ocol0 + ni * 16;
        float bv = bias ? bias[col] : 0.0f;
        #pragma unroll
        for (int mi = 0; mi < 4; mi++) {
            #pragma unroll
            for (int r = 0; r < 4; r++) {
                int row = orow0 + mi * 16 + r;
                if (row >= N) continue;
                float v = acc[mi][ni][r] + bv;
                if (HAS_ADD) v += add[(size_t)row * Md + col];
                if (TANH) v = fast_tanh(v);
                size_t oidx = (size_t)row * Md + col;
                if (EMIT == 0) outf[oidx] = v;
                else if (EMIT == 1) outh[oidx] = bf16_rne(v);
                else { short2 p = split2(v); outh[oidx] = p.x; outl[oidx] = p.y; }
            }
        }
    }
}

// ---------------------------------------------------------------------------
extern "C" void kernel_launch(void* const* d_in, const int* in_sizes, int n_in,
                              void* d_out, int out_size, void* d_ws, size_t ws_size,
                              hipStream_t stream) {
    const int N = N_NODES, E = N_EDGES;

    const float* x[2]   = {(const float*)d_in[0],  (const float*)d_in[1]};
    const int*   ei[2]  = {(const int*)d_in[2],    (const int*)d_in[3]};
    const float* W1l[2] = {(const float*)d_in[4],  (const float*)d_in[10]};
    const float* b1[2]  = {(const float*)d_in[5],  (const float*)d_in[11]};
    const float* W1r[2] = {(const float*)d_in[6],  (const float*)d_in[12]};
    const float* W2l[2] = {(const float*)d_in[7],  (const float*)d_in[13]};
    const float* b2[2]  = {(const float*)d_in[8],  (const float*)d_in[14]};
    const float* W2r[2] = {(const float*)d_in[9],  (const float*)d_in[15]};
    float* out = (float*)d_out;

    // Workspace layout (MiB offsets; all buffers reused across the 2 graphs):
    //   cnt@0 rowptr@256K pos@512K bsum@768K boff@769K adj@1MiB(3.05MiB)
    //   weights(split)@4.25MiB (8 x 64KiB)
    //   xh@5  xl@18  meanh@31 meanl@44  hh@57 hl@82   [MiB]
    //   zh aliases xh@5; aggz(f32) aliases mean@31 (both dead by then)
    char* wsb = (char*)d_ws;
    const size_t MiB = 1u << 20;
    int*   cnt    = (int*)(wsb);
    int*   rowptr = (int*)(wsb + 256 * 1024);
    int*   pos    = (int*)(wsb + 512 * 1024);
    int*   bsum   = (int*)(wsb + 768 * 1024);
    int*   boff   = (int*)(wsb + 769 * 1024);
    int*   adj    = (int*)(wsb + 1 * MiB);
    short* Wbuf   = (short*)(wsb + 4 * MiB + 256 * 1024);
    short* W1lh = Wbuf;          short* W1ll = Wbuf + 32768;
    short* W1rh = Wbuf + 65536;  short* W1rl = Wbuf + 98304;
    short* W2lh = Wbuf + 131072; short* W2ll = Wbuf + 163840;
    short* W2rh = Wbuf + 196608; short* W2rl = Wbuf + 229376;
    short* xh    = (short*)(wsb + 5 * MiB);
    short* xl    = (short*)(wsb + 18 * MiB);
    short* meanh = (short*)(wsb + 31 * MiB);
    short* meanl = (short*)(wsb + 44 * MiB);
    short* hh    = (short*)(wsb + 57 * MiB);
    short* hl    = (short*)(wsb + 82 * MiB);
    short* zh    = xh;                       // alias (x dead after L1 GEMM)
    float* aggz  = (float*)(wsb + 31 * MiB); // alias (mean dead after L1 GEMM)

    const int gemm_rows = (N + TM - 1) / TM;      // 391
    const int agg_blocks = (N * 64 + 255) / 256;  // wave-per-node

    for (int g = 0; g < 2; g++) {
        const int* src = ei[g];
        const int* dst = ei[g] + E;

        // ---- CSR build (counting sort by dst); grid scan
        (void)hipMemsetAsync(cnt, 0, (size_t)N * sizeof(int), stream);
        count_k<<<(E + 255) / 256, 256, 0, stream>>>(dst, cnt, E);
        bsum_k<<<SCAN_NB, 256, 0, stream>>>(cnt, bsum, N);
        boff_k<<<1, 256, 0, stream>>>(bsum, boff, rowptr, SCAN_NB, N);
        scan_blk_k<<<SCAN_NB, 256, 0, stream>>>(cnt, boff, rowptr, pos, N);
        fill_adj_k<<<(E + 255) / 256, 256, 0, stream>>>(src, dst, pos, adj, E);

        // ---- Pre-split x and weights to bf16 hi/lo
        convert_split_k<<<(N * 32 + 255) / 256, 256, 0, stream>>>(x[g], xh, xl, N * 32);
        convert_split_k<<<32, 256, 0, stream>>>(W1l[g], W1lh, W1ll, 8192);
        convert_split_k<<<32, 256, 0, stream>>>(W1r[g], W1rh, W1rl, 8192);
        convert_split_k<<<32, 256, 0, stream>>>(W2l[g], W2lh, W2ll, 8192);
        convert_split_k<<<32, 256, 0, stream>>>(W2r[g], W2rh, W2rl, 8192);

        // ---- Layer 1: mean1 = mean-agg(x_bf16) -> split bf16
        gather_mean_k<0><<<agg_blocks, 256, 0, stream>>>(
            (const unsigned*)xh, rowptr, adj, (unsigned*)meanh, (unsigned*)meanl,
            nullptr, N);
        // h = tanh(mean1@W1l^T + x@W1r^T + b1) -> split bf16 hh/hl  [K=256 -> 256]
        gemm_bf16s_k<2, true, false><<<dim3(256 / TN, gemm_rows), 256, 0, stream>>>(
            meanh, meanl, W1lh, W1ll, 128, xh, xl, W1rh, W1rl, 128,
            nullptr, b1[g], nullptr, hh, hl, N, 256);

        // ---- Layer 2 (linearity): z = h@W2l^T -> bf16 hi only
        gemm_bf16s_k<1, false, false><<<dim3(128 / TN, gemm_rows), 256, 0, stream>>>(
            hh, hl, W2lh, W2ll, 256, nullptr, nullptr, nullptr, nullptr, 0,
            nullptr, nullptr, nullptr, zh, nullptr, N, 128);
        // aggz = mean-agg(z_bf16) -> f32
        gather_mean_k<1><<<agg_blocks, 256, 0, stream>>>(
            (const unsigned*)zh, rowptr, adj, nullptr, nullptr, aggz, N);
        // out = tanh(aggz + h@W2r^T + b2) -> f32  [K=256 -> 128]
        gemm_bf16s_k<0, true, true><<<dim3(128 / TN, gemm_rows), 256, 0, stream>>>(
            hh, hl, W2rh, W2rl, 256, nullptr, nullptr, nullptr, nullptr, 0,
            aggz, b2[g], out + (size_t)g * N * 128, nullptr, nullptr, N, 128);
    }
}

// Round 8
// 721.136 us; speedup vs baseline: 12.4941x; 1.0174x over previous
//
#include <hip/hip_runtime.h>
#include <cstddef>

// Problem constants (from reference setup_inputs)
#define N_NODES 50000
#define N_EDGES 800000

typedef __attribute__((ext_vector_type(8))) short short8;   // 8 bf16 (4 VGPRs)
typedef __attribute__((ext_vector_type(4))) short short4v;  // 4 bf16
typedef __attribute__((ext_vector_type(4))) float f32x4;    // MFMA acc

// ---------------------------------------------------------------------------
// fast tanh via v_exp_f32; abs err ~1e-7, threshold is 2e-2.
__device__ __forceinline__ float fast_tanh(float x) {
    float t = __expf(2.0f * x);
    return 1.0f - 2.0f / (t + 1.0f);
}

// round-to-nearest-even f32 -> bf16 bit pattern
__device__ __forceinline__ short bf16_rne(float x) {
    unsigned u = __float_as_uint(x);
    unsigned r = u + 0x7FFFu + ((u >> 16) & 1u);
    return (short)(r >> 16);
}
// split x ~= hi + lo (both bf16); hi rounded RNE, lo = bf16(x - hi).
__device__ __forceinline__ short2 split2(float x) {
    unsigned u = __float_as_uint(x);
    unsigned r = (u + 0x7FFFu + ((u >> 16) & 1u)) & 0xFFFF0000u;
    short2 p;
    p.x = (short)(r >> 16);
    p.y = bf16_rne(x - __uint_as_float(r));
    return p;
}

// Convert f32 array -> split bf16 hi/lo arrays. One float4 per thread.
__global__ void convert_split_k(const float* __restrict__ src, short* __restrict__ h,
                                short* __restrict__ l, int n4) {
    int i = blockIdx.x * blockDim.x + threadIdx.x;
    if (i >= n4) return;
    float4 v = ((const float4*)src)[i];
    short4v hs, ls; short2 p;
    p = split2(v.x); hs.x = p.x; ls.x = p.y;
    p = split2(v.y); hs.y = p.x; ls.y = p.y;
    p = split2(v.z); hs.z = p.x; ls.z = p.y;
    p = split2(v.w); hs.w = p.x; ls.w = p.y;
    ((short4v*)h)[i] = hs;
    ((short4v*)l)[i] = ls;
}

// ---------------------------------------------------------------------------
// Degree count: cnt[dst]++ per edge (int atomics)
__global__ void count_k(const int* __restrict__ dst, int* __restrict__ cnt, int E) {
    int e = blockIdx.x * blockDim.x + threadIdx.x;
    if (e < E) atomicAdd(&cnt[dst[e]], 1);
}

// ---- 3-phase grid scan -----------------------------------------------------
#define SCAN_NB ((N_NODES + 255) / 256)   // 196 blocks

__global__ __launch_bounds__(256) void bsum_k(const int* __restrict__ cnt,
                                              int* __restrict__ bsum, int N) {
    __shared__ int red[256];
    int i = blockIdx.x * 256 + threadIdx.x;
    int v = (i < N) ? cnt[i] : 0;
    red[threadIdx.x] = v;
    __syncthreads();
    #pragma unroll
    for (int off = 128; off > 0; off >>= 1) {
        if (threadIdx.x < off) red[threadIdx.x] += red[threadIdx.x + off];
        __syncthreads();
    }
    if (threadIdx.x == 0) bsum[blockIdx.x] = red[0];
}

__global__ __launch_bounds__(256) void boff_k(const int* __restrict__ bsum,
                                              int* __restrict__ boff,
                                              int* __restrict__ rowptr,
                                              int nb, int N) {
    __shared__ int s[256];
    int tid = threadIdx.x;
    int v = (tid < nb) ? bsum[tid] : 0;
    s[tid] = v;
    __syncthreads();
    #pragma unroll
    for (int off = 1; off < 256; off <<= 1) {
        int t = (tid >= off) ? s[tid - off] : 0;
        __syncthreads();
        s[tid] += t;
        __syncthreads();
    }
    if (tid < nb) boff[tid] = s[tid] - v;   // exclusive
    if (tid == 255) rowptr[N] = s[255];
}

__global__ __launch_bounds__(256) void scan_blk_k(const int* __restrict__ cnt,
                                                  const int* __restrict__ boff,
                                                  int* __restrict__ rowptr,
                                                  int* __restrict__ pos, int N) {
    __shared__ int s[256];
    int tid = threadIdx.x;
    int i = blockIdx.x * 256 + tid;
    int v = (i < N) ? cnt[i] : 0;
    s[tid] = v;
    __syncthreads();
    #pragma unroll
    for (int off = 1; off < 256; off <<= 1) {
        int t = (tid >= off) ? s[tid - off] : 0;
        __syncthreads();
        s[tid] += t;
        __syncthreads();
    }
    int excl = s[tid] - v + boff[blockIdx.x];
    if (i < N) { rowptr[i] = excl; pos[i] = excl; }
}

// Counting-sort scatter: adj[slot] = src, bucketed by dst (int atomics only)
__global__ void fill_adj_k(const int* __restrict__ src, const int* __restrict__ dst,
                           int* __restrict__ pos, int* __restrict__ adj, int E) {
    int e = blockIdx.x * blockDim.x + threadIdx.x;
    if (e < E) {
        int slot = atomicAdd(&pos[dst[e]], 1);
        adj[slot] = src[e];
    }
}

// ---------------------------------------------------------------------------
// Pull-mean aggregation over bf16 rows (D=128, 256B/row): one wave per node,
// lane owns one uint = 2 bf16 (cols 2*lane, 2*lane+1). f32 accumulate, 8 rows
// in flight.
// OUTM 0: split bf16 hi/lo outputs. OUTM 1: finalize -- out = tanh(mean +
//         preout + bias), f32 (fuses layer-2 epilogue).
template <int OUTM>
__global__ __launch_bounds__(256) void gather_mean_k(
        const unsigned* __restrict__ X2,   // bf16 [N][128] viewed as [N][64] uints
        const int* __restrict__ rowptr, const int* __restrict__ adj,
        unsigned* __restrict__ outh, unsigned* __restrict__ outl,
        const float* __restrict__ preout, const float* __restrict__ bias,
        float* __restrict__ outf, int N) {
    int gw = (blockIdx.x * blockDim.x + threadIdx.x) >> 6;   // node
    int lane = threadIdx.x & 63;
    if (gw >= N) return;
    int beg = rowptr[gw], end = rowptr[gw + 1];
    const unsigned* Xl = X2 + lane;
    float sx = 0.f, sy = 0.f;
    int n = beg;
    for (; n + 8 <= end; n += 8) {
        unsigned u0 = Xl[(size_t)adj[n] * 64];
        unsigned u1 = Xl[(size_t)adj[n + 1] * 64];
        unsigned u2 = Xl[(size_t)adj[n + 2] * 64];
        unsigned u3 = Xl[(size_t)adj[n + 3] * 64];
        unsigned u4 = Xl[(size_t)adj[n + 4] * 64];
        unsigned u5 = Xl[(size_t)adj[n + 5] * 64];
        unsigned u6 = Xl[(size_t)adj[n + 6] * 64];
        unsigned u7 = Xl[(size_t)adj[n + 7] * 64];
        sx += __uint_as_float(u0 << 16) + __uint_as_float(u1 << 16)
            + __uint_as_float(u2 << 16) + __uint_as_float(u3 << 16)
            + __uint_as_float(u4 << 16) + __uint_as_float(u5 << 16)
            + __uint_as_float(u6 << 16) + __uint_as_float(u7 << 16);
        sy += __uint_as_float(u0 & 0xFFFF0000u) + __uint_as_float(u1 & 0xFFFF0000u)
            + __uint_as_float(u2 & 0xFFFF0000u) + __uint_as_float(u3 & 0xFFFF0000u)
            + __uint_as_float(u4 & 0xFFFF0000u) + __uint_as_float(u5 & 0xFFFF0000u)
            + __uint_as_float(u6 & 0xFFFF0000u) + __uint_as_float(u7 & 0xFFFF0000u);
    }
    for (; n < end; n++) {
        unsigned u = Xl[(size_t)adj[n] * 64];
        sx += __uint_as_float(u << 16);
        sy += __uint_as_float(u & 0xFFFF0000u);
    }
    int deg = end - beg;
    float inv = 1.0f / (float)(deg > 0 ? deg : 1);
    float mx = sx * inv, my = sy * inv;
    if (OUTM == 0) {
        short2 px = split2(mx), py = split2(my);
        outh[(size_t)gw * 64 + lane] =
            (unsigned)(unsigned short)px.x | ((unsigned)(unsigned short)py.x << 16);
        outl[(size_t)gw * 64 + lane] =
            (unsigned)(unsigned short)px.y | ((unsigned)(unsigned short)py.y << 16);
    } else {
        float2 po = ((const float2*)preout)[(size_t)gw * 64 + lane];
        float2 bb = ((const float2*)bias)[lane];
        float2 o;
        o.x = fast_tanh(mx + po.x + bb.x);
        o.y = fast_tanh(my + po.y + bb.y);
        ((float2*)outf)[(size_t)gw * 64 + lane] = o;
    }
}

// ---------------------------------------------------------------------------
// Split-bf16 MFMA fused GEMM with REGISTER-PREFETCH pipeline:
//   out[r,c] = act( A1[r,:]·B1[c,:] + A2[r,:]·B2[c,:] + add[r,c] + bias[c] )
// Tile k+1's global loads issue before tile k's MFMAs (vmcnt drain lands
// after the compute), hiding load latency at low occupancy.
// 128x128 tile, BK=32, 4 waves in 2x2, each 64x64 via 4x4 of 16x16x32 mfma.
// Grid: (cols fastest, rows).
// EMIT: 0 = f32 out; 2 = split bf16 hi+lo out;
//       3 = dual: block col-half 0 -> bf16-hi z (outh, stride Md/2),
//                 col-half 1 -> f32 preout (outf, stride Md/2), no bias/act.
#define TM 128
#define TN 128
#define TK 32
#define LSTR 40   // LDS row stride in shorts (32 data + 8 pad; 80B, 16B-aligned)

template <int EMIT, bool TANH>
__global__ __launch_bounds__(256)
void gemm_bf16s_k(const short* __restrict__ A1h, const short* __restrict__ A1l,
                  const short* __restrict__ B1h, const short* __restrict__ B1l, int K1,
                  const short* __restrict__ A2h, const short* __restrict__ A2l,
                  const short* __restrict__ B2h, const short* __restrict__ B2l, int K2,
                  const float* __restrict__ bias,
                  float* __restrict__ outf, short* __restrict__ outh,
                  short* __restrict__ outl, int N, int Md) {
    __shared__ short sAh[TM][LSTR], sAl[TM][LSTR];
    __shared__ short sBh[TN][LSTR], sBl[TN][LSTR];

    const int tid = threadIdx.x;
    const int lane = tid & 63;
    const int wave = tid >> 6;              // 0..3
    const int waveM = (wave & 1) * 64;
    const int waveN = (wave >> 1) * 64;
    const int rowBase = blockIdx.y * TM;
    const int colBase = blockIdx.x * TN;
    const int Ktot = K1 + K2;

    // staging coords: chunk j covers row rj, 16B col cj (of 4) in the k-tile
    const int r0 = tid >> 2,           c0 = tid & 3;
    const int r1 = (tid + 256) >> 2,   c1 = (tid + 256) & 3;
    const int gr0 = rowBase + r0,      gr1 = rowBase + r1;

    f32x4 acc[4][4] = {};
    short8 pA[2][2], pB[2][2];   // [chunk][h/l]

    auto load_tile = [&](int k0) {
        const short *Ah, *Al, *Bh, *Bl; int ko, ld;
        if (k0 < K1) { Ah = A1h; Al = A1l; Bh = B1h; Bl = B1l; ko = k0;      ld = K1; }
        else         { Ah = A2h; Al = A2l; Bh = B2h; Bl = B2l; ko = k0 - K1; ld = K2; }
        short8 z = {0,0,0,0,0,0,0,0};
        size_t a0 = (size_t)gr0 * ld + ko + c0 * 8;
        size_t a1 = (size_t)gr1 * ld + ko + c1 * 8;
        pA[0][0] = gr0 < N ? *(const short8*)(Ah + a0) : z;
        pA[0][1] = gr0 < N ? *(const short8*)(Al + a0) : z;
        pA[1][0] = gr1 < N ? *(const short8*)(Ah + a1) : z;
        pA[1][1] = gr1 < N ? *(const short8*)(Al + a1) : z;
        size_t b0 = (size_t)(colBase + r0) * ld + ko + c0 * 8;
        size_t b1 = (size_t)(colBase + r1) * ld + ko + c1 * 8;
        pB[0][0] = *(const short8*)(Bh + b0);
        pB[0][1] = *(const short8*)(Bl + b0);
        pB[1][0] = *(const short8*)(Bh + b1);
        pB[1][1] = *(const short8*)(Bl + b1);
    };
    auto store_tile = [&]() {
        *(short8*)&sAh[r0][c0 * 8] = pA[0][0];
        *(short8*)&sAl[r0][c0 * 8] = pA[0][1];
        *(short8*)&sAh[r1][c1 * 8] = pA[1][0];
        *(short8*)&sAl[r1][c1 * 8] = pA[1][1];
        *(short8*)&sBh[r0][c0 * 8] = pB[0][0];
        *(short8*)&sBl[r0][c0 * 8] = pB[0][1];
        *(short8*)&sBh[r1][c1 * 8] = pB[1][0];
        *(short8*)&sBl[r1][c1 * 8] = pB[1][1];
    };

    const int fm = lane & 15;
    const int fq = (lane >> 4) * 8;
    short8 fah[4], fal[4], fbh[4], fbl[4];
    auto read_frags = [&]() {
        #pragma unroll
        for (int mi = 0; mi < 4; mi++) {
            fah[mi] = *(const short8*)&sAh[waveM + mi * 16 + fm][fq];
            fal[mi] = *(const short8*)&sAl[waveM + mi * 16 + fm][fq];
        }
        #pragma unroll
        for (int ni = 0; ni < 4; ni++) {
            fbh[ni] = *(const short8*)&sBh[waveN + ni * 16 + fm][fq];
            fbl[ni] = *(const short8*)&sBl[waveN + ni * 16 + fm][fq];
        }
    };
    auto mfma_all = [&]() {
        #pragma unroll
        for (int mi = 0; mi < 4; mi++)
            #pragma unroll
            for (int ni = 0; ni < 4; ni++) {
                acc[mi][ni] = __builtin_amdgcn_mfma_f32_16x16x32_bf16(
                    fah[mi], fbh[ni], acc[mi][ni], 0, 0, 0);
                acc[mi][ni] = __builtin_amdgcn_mfma_f32_16x16x32_bf16(
                    fah[mi], fbl[ni], acc[mi][ni], 0, 0, 0);
                acc[mi][ni] = __builtin_amdgcn_mfma_f32_16x16x32_bf16(
                    fal[mi], fbh[ni], acc[mi][ni], 0, 0, 0);
            }
    };

    load_tile(0);
    store_tile();
    __syncthreads();

    for (int k0 = TK; k0 < Ktot; k0 += TK) {
        read_frags();
        load_tile(k0);      // prefetch next tile; overlaps the MFMAs below
        mfma_all();
        __syncthreads();    // all ds_reads of current tile done
        store_tile();       // vmcnt drain happens here, after compute
        __syncthreads();
    }
    read_frags();
    mfma_all();

    // Epilogue. C/D layout (16x16): col = lane&15, row = (lane>>4)*4 + reg.
    const int orow0 = rowBase + waveM + (lane >> 4) * 4;
    const int ocol0 = colBase + waveN + (lane & 15);
    const int half = Md >> 1;
    #pragma unroll
    for (int ni = 0; ni < 4; ni++) {
        int col = ocol0 + ni * 16;
        float bv = bias ? bias[col] : 0.0f;
        #pragma unroll
        for (int mi = 0; mi < 4; mi++) {
            #pragma unroll
            for (int r = 0; r < 4; r++) {
                int row = orow0 + mi * 16 + r;
                if (row >= N) continue;
                float v = acc[mi][ni][r] + bv;
                if (TANH) v = fast_tanh(v);
                if (EMIT == 0) {
                    outf[(size_t)row * Md + col] = v;
                } else if (EMIT == 2) {
                    short2 p = split2(v);
                    size_t oidx = (size_t)row * Md + col;
                    outh[oidx] = p.x; outl[oidx] = p.y;
                } else { // EMIT == 3: dual (block-uniform branch)
                    size_t oidx = (size_t)row * half + (col & (half - 1));
                    if (col < half) outh[oidx] = bf16_rne(v);
                    else            outf[oidx] = v;
                }
            }
        }
    }
}

// ---------------------------------------------------------------------------
extern "C" void kernel_launch(void* const* d_in, const int* in_sizes, int n_in,
                              void* d_out, int out_size, void* d_ws, size_t ws_size,
                              hipStream_t stream) {
    const int N = N_NODES, E = N_EDGES;

    const float* x[2]   = {(const float*)d_in[0],  (const float*)d_in[1]};
    const int*   ei[2]  = {(const int*)d_in[2],    (const int*)d_in[3]};
    const float* W1l[2] = {(const float*)d_in[4],  (const float*)d_in[10]};
    const float* b1[2]  = {(const float*)d_in[5],  (const float*)d_in[11]};
    const float* W1r[2] = {(const float*)d_in[6],  (const float*)d_in[12]};
    const float* W2l[2] = {(const float*)d_in[7],  (const float*)d_in[13]};
    const float* b2[2]  = {(const float*)d_in[8],  (const float*)d_in[14]};
    const float* W2r[2] = {(const float*)d_in[9],  (const float*)d_in[15]};
    float* out = (float*)d_out;

    // Workspace layout (MiB offsets; reused across the 2 graphs):
    //   cnt@0 rowptr@256K pos@512K bsum@768K boff@769K adj@1MiB(3.05MiB)
    //   weights(split)@4.25MiB: W1lh/W1ll/W1rh/W1rl 32768 shorts each,
    //                           W2cath/W2catl 65536 shorts each (=512KiB total)
    //   xh@5  xl@18  meanh@31 meanl@44  hh@57 hl@82   [MiB]
    //   zh aliases xh@5 (x dead after L1 GEMM)
    //   preout(f32, 25.6MB) aliases mean@31 (mean dead after L1 GEMM)
    char* wsb = (char*)d_ws;
    const size_t MiB = 1u << 20;
    int*   cnt    = (int*)(wsb);
    int*   rowptr = (int*)(wsb + 256 * 1024);
    int*   pos    = (int*)(wsb + 512 * 1024);
    int*   bsum   = (int*)(wsb + 768 * 1024);
    int*   boff   = (int*)(wsb + 769 * 1024);
    int*   adj    = (int*)(wsb + 1 * MiB);
    short* Wbuf   = (short*)(wsb + 4 * MiB + 256 * 1024);
    short* W1lh   = Wbuf;           short* W1ll   = Wbuf + 32768;
    short* W1rh   = Wbuf + 65536;   short* W1rl   = Wbuf + 98304;
    short* W2cath = Wbuf + 131072;  short* W2catl = Wbuf + 196608;
    short* xh     = (short*)(wsb + 5 * MiB);
    short* xl     = (short*)(wsb + 18 * MiB);
    short* meanh  = (short*)(wsb + 31 * MiB);
    short* meanl  = (short*)(wsb + 44 * MiB);
    short* hh     = (short*)(wsb + 57 * MiB);
    short* hl     = (short*)(wsb + 82 * MiB);
    short* zh     = xh;                        // alias
    float* preout = (float*)(wsb + 31 * MiB);  // alias over mean

    const int gemm_rows = (N + TM - 1) / TM;      // 391
    const int agg_blocks = (N * 64 + 255) / 256;  // wave-per-node

    for (int g = 0; g < 2; g++) {
        const int* src = ei[g];
        const int* dst = ei[g] + E;

        // ---- CSR build (counting sort by dst); grid scan
        (void)hipMemsetAsync(cnt, 0, (size_t)N * sizeof(int), stream);
        count_k<<<(E + 255) / 256, 256, 0, stream>>>(dst, cnt, E);
        bsum_k<<<SCAN_NB, 256, 0, stream>>>(cnt, bsum, N);
        boff_k<<<1, 256, 0, stream>>>(bsum, boff, rowptr, SCAN_NB, N);
        scan_blk_k<<<SCAN_NB, 256, 0, stream>>>(cnt, boff, rowptr, pos, N);
        fill_adj_k<<<(E + 255) / 256, 256, 0, stream>>>(src, dst, pos, adj, E);

        // ---- Pre-split x and weights to bf16 hi/lo
        convert_split_k<<<(N * 32 + 255) / 256, 256, 0, stream>>>(x[g], xh, xl, N * 32);
        convert_split_k<<<32, 256, 0, stream>>>(W1l[g], W1lh, W1ll, 8192);
        convert_split_k<<<32, 256, 0, stream>>>(W1r[g], W1rh, W1rl, 8192);
        // W2cat rows 0-127 = W2l, rows 128-255 = W2r (each row K=256)
        convert_split_k<<<32, 256, 0, stream>>>(W2l[g], W2cath, W2catl, 8192);
        convert_split_k<<<32, 256, 0, stream>>>(W2r[g], W2cath + 32768,
                                                W2catl + 32768, 8192);

        // ---- Layer 1: mean1 = mean-agg(x_bf16) -> split bf16
        gather_mean_k<0><<<agg_blocks, 256, 0, stream>>>(
            (const unsigned*)xh, rowptr, adj, (unsigned*)meanh, (unsigned*)meanl,
            nullptr, nullptr, nullptr, N);
        // h = tanh(mean1@W1l^T + x@W1r^T + b1) -> split bf16 hh/hl  [K=256 -> 256]
        gemm_bf16s_k<2, true><<<dim3(256 / TN, gemm_rows), 256, 0, stream>>>(
            meanh, meanl, W1lh, W1ll, 128, xh, xl, W1rh, W1rl, 128,
            b1[g], nullptr, hh, hl, N, 256);

        // ---- Layer 2 fused: [z | preout] = h @ [W2l | W2r]^T   [K=256 -> 256]
        //      cols 0-127 -> zh (bf16-hi), cols 128-255 -> preout (f32)
        gemm_bf16s_k<3, false><<<dim3(256 / TN, gemm_rows), 256, 0, stream>>>(
            hh, hl, W2cath, W2catl, 256, nullptr, nullptr, nullptr, nullptr, 0,
            nullptr, preout, zh, nullptr, N, 256);
        // out = tanh(mean-agg(z) + preout + b2)  (fused gather+finalize)
        gather_mean_k<1><<<agg_blocks, 256, 0, stream>>>(
            (const unsigned*)zh, rowptr, adj, nullptr, nullptr,
            preout, b2[g], out + (size_t)g * N * 128, N);
    }
}